// Round 8
// baseline (464.150 us; speedup 1.0000x reference)
//
#include <hip/hip_runtime.h>

#define B_ 16
#define L_ 512
#define D_ 768
#define H_ 4
#define A_ 100
#define DK_ 25
#define P_ 3
#define XP_ 128   // padded row stride for x/x1/x2/axb

// ------------------------------------------- K0: wT[d][a] = ln_a[d]*Wxx_w[a][d], pad a to 128
__global__ __launch_bounds__(256) void k_wprep(const float* __restrict__ Wxx_w,
                                               const float* __restrict__ ln_a,
                                               float* __restrict__ wT)
{
    const int idx = blockIdx.x * 256 + threadIdx.x;     // 768*128
    const int d = idx >> 7, a = idx & 127;
    wT[idx] = (a < A_) ? ln_a[d] * Wxx_w[(size_t)a * D_ + d] : 0.f;
}

// ------------------------------------------- K0e: colsum[a] = sum_d ln_a[d]*Wxx[a][d]; basev[a] = ln_b@Wxx^T + Wxx_b
__global__ __launch_bounds__(128) void k_vecprep(const float* __restrict__ Wxx_w,
                                                 const float* __restrict__ ln_a,
                                                 const float* __restrict__ ln_b,
                                                 const float* __restrict__ Wxx_b,
                                                 float* __restrict__ colsum,
                                                 float* __restrict__ basev)
{
    const int a = threadIdx.x;
    float cs = 0.f, bs = 0.f;
    if (a < A_) {
        const float* wr = Wxx_w + (size_t)a * D_;
        for (int d = 0; d < D_; ++d) {
            const float w = wr[d];
            cs += ln_a[d] * w;
            bs += ln_b[d] * w;
        }
        bs += Wxx_b[a];
    }
    colsum[a] = (a < A_) ? cs : 0.f;
    basev[a]  = (a < A_) ? bs : 0.f;
}

// ------------------------------------- K0b: aggT[c][k][n] = agg_w[n][c*100+k], pad n to 128
__global__ __launch_bounds__(256) void k_aggprep(const float* __restrict__ agg_w,
                                                 float* __restrict__ aggT)
{
    const int idx = blockIdx.x * 256 + threadIdx.x;     // 3*100*128 = 38400
    const int n = idx & 127, k = (idx >> 7) % A_, c = idx / (128 * A_);
    aggT[idx] = (n < A_) ? agg_w[(size_t)n * (3 * A_) + c * A_ + k] : 0.f;
}

// ------------------------------------- K0c: qkT[k][n]: n<128 -> q_w[n][k], n>=128 -> k_w[n-128][k]
__global__ __launch_bounds__(256) void k_qkprep(const float* __restrict__ q_w,
                                                const float* __restrict__ k_w,
                                                float* __restrict__ qkT)
{
    const int idx = blockIdx.x * 256 + threadIdx.x;     // 100*256 = 25600
    const int n = idx & 255, k = idx >> 8;
    const int half = n >> 7, a = n & 127;
    const float* w = half ? k_w : q_w;
    qkT[idx] = (a < A_) ? w[(size_t)a * A_ + k] : 0.f;
}

// ------------------------------------- K0d: WT[k][n] = W_w[n][k], pad n to 128
__global__ __launch_bounds__(256) void k_wprep2(const float* __restrict__ W_w,
                                                float* __restrict__ WT)
{
    const int idx = blockIdx.x * 256 + threadIdx.x;     // 100*128 = 12800
    const int n = idx & 127, k = idx >> 7;
    WT[idx] = (n < A_) ? W_w[(size_t)n * A_ + k] : 0.f;
}

// ------------------- K1: LN-folded GEMM with fused stats: x = rd*(seq@W2) - rd*mean*colsum + basev
// 128 threads, 16 rows x 128 cols, grid 512 (2 blocks/CU). Stats accumulated in-loop.
__global__ __launch_bounds__(128) void k_lnx(
    const float* __restrict__ seq, const float* __restrict__ wT,
    const float* __restrict__ colsum, const float* __restrict__ basev,
    float* __restrict__ xp)
{
    __shared__ float ss[16][36];        // raw seq chunk, +4 pad
    __shared__ float ws[32][128];
    const int tid = threadIdx.x;
    const int row0 = blockIdx.x * 16;
    const int c4 = tid & 31, rg = tid >> 5;   // rg in 0..3 -> rows rg*4..rg*4+3

    float4 acc[4];
    float rsum[4] = {0.f, 0.f, 0.f, 0.f};
    float rsq[4]  = {0.f, 0.f, 0.f, 0.f};
    #pragma unroll
    for (int i = 0; i < 4; ++i) { acc[i].x = acc[i].y = acc[i].z = acc[i].w = 0.f; }

    for (int kc = 0; kc < 24; ++kc) {
        {   // stage seq chunk: 16 rows x 32 k = 128 float4, 1/thread
            const int r = tid >> 3, k4 = tid & 7;
            *(float4*)&ss[r][k4 * 4] =
                *(const float4*)(seq + (size_t)(row0 + r) * D_ + kc * 32 + k4 * 4);
        }
        #pragma unroll
        for (int t = 0; t < 8; ++t) {   // stage weight chunk: 1024 float4, 8/thread
            const int idx = tid + t * 128;
            const int k = idx >> 5, cc = idx & 31;
            *(float4*)&ws[k][cc * 4] = *(const float4*)(wT + (size_t)(kc * 32 + k) * 128 + cc * 4);
        }
        __syncthreads();
        #pragma unroll 2
        for (int k = 0; k < 32; k += 4) {
            float4 sv[4];
            #pragma unroll
            for (int i = 0; i < 4; ++i) {
                sv[i] = *(float4*)&ss[rg * 4 + i][k];
                rsum[i] += sv[i].x + sv[i].y + sv[i].z + sv[i].w;
                rsq[i]  += sv[i].x * sv[i].x + sv[i].y * sv[i].y
                         + sv[i].z * sv[i].z + sv[i].w * sv[i].w;
            }
            #pragma unroll
            for (int j = 0; j < 4; ++j) {
                float4 w4 = *(float4*)&ws[k + j][c4 * 4];
                #pragma unroll
                for (int i = 0; i < 4; ++i) {
                    const float sj = ((float*)&sv[i])[j];
                    acc[i].x += sj * w4.x; acc[i].y += sj * w4.y;
                    acc[i].z += sj * w4.z; acc[i].w += sj * w4.w;
                }
            }
        }
        __syncthreads();
    }

    const float4 cs4 = ((const float4*)colsum)[c4];
    const float4 bs4 = ((const float4*)basev)[c4];
    #pragma unroll
    for (int i = 0; i < 4; ++i) {
        const float m = rsum[i] * (1.0f / 768.0f);
        const float var = (rsq[i] - 768.0f * m * m) * (1.0f / 767.0f);   // ddof=1
        const float rd = 1.0f / (sqrtf(var) + 1e-6f);                     // std + EPS
        float4 o;
        o.x = rd * (acc[i].x - m * cs4.x) + bs4.x;
        o.y = rd * (acc[i].y - m * cs4.y) + bs4.y;
        o.z = rd * (acc[i].z - m * cs4.z) + bs4.z;
        o.w = rd * (acc[i].w - m * cs4.w) + bs4.w;
        *(float4*)(xp + (size_t)(row0 + rg * 4 + i) * XP_ + c4 * 4) = o;  // pad cols -> 0
    }
}

// ------------------- K2: q/k = x @ [q_w|k_w]^T + bias  (tiled GEMM); qt/kt (B,L,100)
__global__ __launch_bounds__(256) void k_qkg(
    const float* __restrict__ xp, const float* __restrict__ qkT,
    const float* __restrict__ q_b, const float* __restrict__ k_b,
    float* __restrict__ qt, float* __restrict__ kt)
{
    __shared__ float ss[32][104];
    __shared__ float ws[A_][128];
    const int tid = threadIdx.x;
    const int row0 = blockIdx.x * 32;
    const int half = blockIdx.y;
    const int c4 = tid & 31, rg = tid >> 5;

    for (int idx = tid; idx < 32 * 25; idx += 256) {
        const int r = idx / 25, k4 = idx % 25;
        *(float4*)&ss[r][k4 * 4] = *(const float4*)(xp + (size_t)(row0 + r) * XP_ + k4 * 4);
    }
    for (int idx = tid; idx < A_ * 32; idx += 256) {
        const int k = idx >> 5, cc = idx & 31;
        *(float4*)&ws[k][cc * 4] = *(const float4*)(qkT + (size_t)k * 256 + half * 128 + cc * 4);
    }
    __syncthreads();

    float4 acc[4];
    #pragma unroll
    for (int i = 0; i < 4; ++i) { acc[i].x = acc[i].y = acc[i].z = acc[i].w = 0.f; }
    #pragma unroll 5
    for (int k = 0; k < A_; k += 4) {
        float4 sv[4];
        #pragma unroll
        for (int i = 0; i < 4; ++i) sv[i] = *(float4*)&ss[rg * 4 + i][k];
        #pragma unroll
        for (int j = 0; j < 4; ++j) {
            float4 w4 = *(float4*)&ws[k + j][c4 * 4];
            #pragma unroll
            for (int i = 0; i < 4; ++i) {
                const float sj = ((float*)&sv[i])[j];
                acc[i].x += sj * w4.x; acc[i].y += sj * w4.y;
                acc[i].z += sj * w4.z; acc[i].w += sj * w4.w;
            }
        }
    }

    if (c4 < 25) {
        const float4 bias = ((const float4*)(half ? k_b : q_b))[c4];
        float* dst = half ? kt : qt;
        #pragma unroll
        for (int i = 0; i < 4; ++i) {
            float4 o;
            o.x = acc[i].x + bias.x; o.y = acc[i].y + bias.y;
            o.z = acc[i].z + bias.z; o.w = acc[i].w + bias.w;
            *(float4*)(dst + (size_t)(row0 + rg * 4 + i) * A_ + c4 * 4) = o;
        }
    }
}

// --------------- K3a: es[bh][i][j] = (mask? q.k/5 : -1e9) + syn   (64x64 tile GEMM, K=25)
__global__ __launch_bounds__(256) void k_sgemm(
    const float* __restrict__ qt, const float* __restrict__ kt,
    const float* __restrict__ syn, const int* __restrict__ src_mask,
    float* __restrict__ es)
{
    __shared__ float qs[DK_][64];
    __shared__ float ks[DK_][64];
    __shared__ int ms[64];
    const int tid = threadIdx.x;
    const int bh = blockIdx.z;
    const int b = bh >> 2, h = bh & 3;
    const int i0 = blockIdx.x * 64, j0 = blockIdx.y * 64;
    const float* qbase = qt + ((size_t)b * L_ + i0) * A_ + h * DK_;
    const float* kbase = kt + ((size_t)b * L_ + j0) * A_ + h * DK_;
    {
        const int r = tid >> 2, c = tid & 3;
        #pragma unroll
        for (int k = 0; k < 7; ++k) {
            const int d = c + 4 * k;
            if (d < DK_) {
                qs[d][r] = qbase[(size_t)r * A_ + d];
                ks[d][r] = kbase[(size_t)r * A_ + d];
            }
        }
        if (tid < 64) ms[tid] = src_mask[b * L_ + j0 + tid];
    }
    __syncthreads();
    const int ty = tid >> 4, tx = tid & 15;
    float acc[4][4] = {};
    #pragma unroll 5
    for (int d = 0; d < DK_; ++d) {
        float4 qv = *(const float4*)&qs[d][ty * 4];
        float4 kv = *(const float4*)&ks[d][tx * 4];
        const float q[4] = {qv.x, qv.y, qv.z, qv.w};
        const float kk[4] = {kv.x, kv.y, kv.z, kv.w};
        #pragma unroll
        for (int ii = 0; ii < 4; ++ii)
            #pragma unroll
            for (int jj = 0; jj < 4; ++jj)
                acc[ii][jj] += q[ii] * kk[jj];
    }
    const int irow = i0 + ty * 4, jcol = j0 + tx * 4;
    const int m0 = ms[tx * 4], m1 = ms[tx * 4 + 1], m2 = ms[tx * 4 + 2], m3 = ms[tx * 4 + 3];
    #pragma unroll
    for (int ii = 0; ii < 4; ++ii) {
        const size_t o = ((size_t)bh * L_ + irow + ii) * L_ + jcol;
        float4 sv = *(const float4*)(syn + o);
        float4 w;
        w.x = (m0 ? acc[ii][0] * 0.2f : -1e9f) + sv.x;
        w.y = (m1 ? acc[ii][1] * 0.2f : -1e9f) + sv.y;
        w.z = (m2 ? acc[ii][2] * 0.2f : -1e9f) + sv.z;
        w.w = (m3 ? acc[ii][3] * 0.2f : -1e9f) + sv.w;
        *(float4*)(es + o) = w;
    }
}

// --------------- K3b: softmax over j per (b,h,i); adjsum -> es plane0, wadj -> plane1
__global__ __launch_bounds__(256) void k_softmax(
    const float* __restrict__ Wx_w, float* __restrict__ es)
{
    __shared__ float ps[H_][L_];
    __shared__ float cs[H_];
    const int tid = threadIdx.x, r = blockIdx.x;
    const int b = r >> 9, i = r & 511;
    const int h = tid >> 6, lane = tid & 63;
    if (tid < H_) cs[tid] = Wx_w[tid] + Wx_w[204 + tid] + Wx_w[408 + tid] + Wx_w[612 + tid];
    float* row = es + (((size_t)(b * H_ + h)) * L_ + i) * L_;
    float4 v0 = ((const float4*)row)[lane];
    float4 v1 = ((const float4*)row)[lane + 64];
    float mx = fmaxf(fmaxf(fmaxf(v0.x, v0.y), fmaxf(v0.z, v0.w)),
                     fmaxf(fmaxf(v1.x, v1.y), fmaxf(v1.z, v1.w)));
    #pragma unroll
    for (int o = 32; o; o >>= 1) mx = fmaxf(mx, __shfl_xor(mx, o));
    float4 e0, e1;
    e0.x = __expf(v0.x - mx); e0.y = __expf(v0.y - mx);
    e0.z = __expf(v0.z - mx); e0.w = __expf(v0.w - mx);
    e1.x = __expf(v1.x - mx); e1.y = __expf(v1.y - mx);
    e1.z = __expf(v1.z - mx); e1.w = __expf(v1.w - mx);
    float sum = e0.x + e0.y + e0.z + e0.w + e1.x + e1.y + e1.z + e1.w;
    #pragma unroll
    for (int o = 32; o; o >>= 1) sum += __shfl_xor(sum, o);
    const float inv = 1.0f / sum;
    e0.x *= inv; e0.y *= inv; e0.z *= inv; e0.w *= inv;
    e1.x *= inv; e1.y *= inv; e1.z *= inv; e1.w *= inv;
    *(float4*)&ps[h][lane * 4] = e0;
    *(float4*)&ps[h][(lane + 64) * 4] = e1;
    __syncthreads();
    float* arow = es + (((size_t)(b * H_ + 0)) * L_ + i) * L_;
    float* wrow = es + (((size_t)(b * H_ + 1)) * L_ + i) * L_;
    const int t = tid & 127;
    float4 p0 = *(float4*)&ps[0][t * 4];
    float4 p1 = *(float4*)&ps[1][t * 4];
    float4 p2 = *(float4*)&ps[2][t * 4];
    float4 p3 = *(float4*)&ps[3][t * 4];
    if (tid < 128) {
        float4 o;
        o.x = p0.x + p1.x + p2.x + p3.x;
        o.y = p0.y + p1.y + p2.y + p3.y;
        o.z = p0.z + p1.z + p2.z + p3.z;
        o.w = p0.w + p1.w + p2.w + p3.w;
        *(float4*)(arow + t * 4) = o;
    } else {
        const float c0 = cs[0], c1 = cs[1], c2 = cs[2], c3 = cs[3];
        float4 o;
        o.x = c0 * p0.x + c1 * p1.x + c2 * p2.x + c3 * p3.x;
        o.y = c0 * p0.y + c1 * p1.y + c2 * p2.y + c3 * p3.y;
        o.z = c0 * p0.z + c1 * p1.z + c2 * p2.z + c3 * p3.z;
        o.w = c0 * p0.w + c1 * p1.w + c2 * p2.w + c3 * p3.w;
        *(float4*)(wrow + t * 4) = o;
    }
}

// ------------- K4a: axb = (adj @ x)/H [+ extras]; 128 threads, 16 rows, grid 512
template<int LAYER2>
__global__ __launch_bounds__(128) void k_axg(
    const float* __restrict__ adj, const float* __restrict__ xp,
    const float* __restrict__ S, const float* __restrict__ T,
    const float* __restrict__ Vv, const float* __restrict__ Wx_b,
    float* __restrict__ axb)
{
    __shared__ float ss[16][36];        // adj chunk, +4 pad
    __shared__ float ws[32][128];       // x chunk
    const int tid = threadIdx.x;
    const int row0 = blockIdx.x * 16;       // global row in [0, B*L)
    const int b = row0 >> 9, i0 = row0 & 511;
    const float* adjb = adj + (size_t)b * 4 * L_ * L_;
    const float* xpb = xp + (size_t)b * L_ * XP_;
    const int c4 = tid & 31, rg = tid >> 5;
    float4 acc[4];
    #pragma unroll
    for (int i = 0; i < 4; ++i) { acc[i].x = acc[i].y = acc[i].z = acc[i].w = 0.f; }

    for (int kc = 0; kc < 16; ++kc) {
        {
            const int r = tid >> 3, k4 = tid & 7;
            *(float4*)&ss[r][k4 * 4] =
                *(const float4*)(adjb + (size_t)(i0 + r) * L_ + kc * 32 + k4 * 4);
        }
        #pragma unroll
        for (int t = 0; t < 8; ++t) {
            const int idx = tid + t * 128;
            const int k = idx >> 5, cc = idx & 31;
            *(float4*)&ws[k][cc * 4] =
                *(const float4*)(xpb + (size_t)(kc * 32 + k) * XP_ + cc * 4);
        }
        __syncthreads();
        #pragma unroll 2
        for (int k = 0; k < 32; k += 4) {
            float4 sv[4];
            #pragma unroll
            for (int i = 0; i < 4; ++i) sv[i] = *(float4*)&ss[rg * 4 + i][k];
            #pragma unroll
            for (int j = 0; j < 4; ++j) {
                float4 w4 = *(float4*)&ws[k + j][c4 * 4];
                #pragma unroll
                for (int i = 0; i < 4; ++i) {
                    const float sj = ((float*)&sv[i])[j];
                    acc[i].x += sj * w4.x; acc[i].y += sj * w4.y;
                    acc[i].z += sj * w4.z; acc[i].w += sj * w4.w;
                }
            }
        }
        __syncthreads();
    }

    float wb = 0.f;
    float4 Sv = {0.f, 0.f, 0.f, 0.f}, Tv = {0.f, 0.f, 0.f, 0.f};
    if (LAYER2) {
        wb = Wx_b[0] + Wx_b[1] + Wx_b[2] + Wx_b[3];
        if (c4 < 25) {
            Sv = ((const float4*)(S + b * A_))[c4];
            Tv = ((const float4*)(T + b * A_))[c4];
        }
    }
    #pragma unroll
    for (int i = 0; i < 4; ++i) {
        const int grow = row0 + rg * 4 + i;
        const float vv = LAYER2 ? (Vv[grow] + wb) : 0.f;
        float4 o;
        o.x = (acc[i].x + Sv.x + vv * Tv.x) * 0.25f;
        o.y = (acc[i].y + Sv.y + vv * Tv.y) * 0.25f;
        o.z = (acc[i].z + Sv.z + vv * Tv.z) * 0.25f;
        o.w = (acc[i].w + Sv.w + vv * Tv.w) * 0.25f;
        *(float4*)(axb + (size_t)grow * XP_ + c4 * 4) = o;   // pad cols -> 0
    }
}

// ------------- K4b: xout = relu(axb @ W^T + b); 128 threads, 16 rows, grid 512
__global__ __launch_bounds__(128) void k_xw(
    const float* __restrict__ axb, const float* __restrict__ WT,
    const float* __restrict__ W_b, float* __restrict__ xout)
{
    __shared__ float ss[16][104];
    __shared__ float ws[A_][128];
    const int tid = threadIdx.x;
    const int row0 = blockIdx.x * 16;
    const int c4 = tid & 31, rg = tid >> 5;

    for (int idx = tid; idx < 16 * 25; idx += 128) {
        const int r = idx / 25, k4 = idx % 25;
        *(float4*)&ss[r][k4 * 4] = *(const float4*)(axb + (size_t)(row0 + r) * XP_ + k4 * 4);
    }
    for (int idx = tid; idx < A_ * 32; idx += 128) {
        const int k = idx >> 5, cc = idx & 31;
        *(float4*)&ws[k][cc * 4] = *(const float4*)(WT + (size_t)k * 128 + cc * 4);
    }
    __syncthreads();

    float4 acc[4];
    #pragma unroll
    for (int i = 0; i < 4; ++i) { acc[i].x = acc[i].y = acc[i].z = acc[i].w = 0.f; }
    #pragma unroll 5
    for (int k = 0; k < A_; k += 4) {
        float4 sv[4];
        #pragma unroll
        for (int i = 0; i < 4; ++i) sv[i] = *(float4*)&ss[rg * 4 + i][k];
        #pragma unroll
        for (int j = 0; j < 4; ++j) {
            float4 w4 = *(float4*)&ws[k + j][c4 * 4];
            #pragma unroll
            for (int i = 0; i < 4; ++i) {
                const float sj = ((float*)&sv[i])[j];
                acc[i].x += sj * w4.x; acc[i].y += sj * w4.y;
                acc[i].z += sj * w4.z; acc[i].w += sj * w4.w;
            }
        }
    }

    float4 bias = {0.f, 0.f, 0.f, 0.f};
    if (c4 < 25) bias = ((const float4*)W_b)[c4];
    #pragma unroll
    for (int i = 0; i < 4; ++i) {
        float4 o;
        o.x = fmaxf(acc[i].x + bias.x, 0.f); o.y = fmaxf(acc[i].y + bias.y, 0.f);
        o.z = fmaxf(acc[i].z + bias.z, 0.f); o.w = fmaxf(acc[i].w + bias.w, 0.f);
        *(float4*)(xout + (size_t)(row0 + rg * 4 + i) * XP_ + c4 * 4) = o;  // WT pad -> 0
    }
}

// ---------------- K5: rank-1 extras for layer 2: Vv (B,L), T,S (B,A); zero pooled
__global__ __launch_bounds__(256) void k_extras(
    const float* __restrict__ x1, const float* __restrict__ Wx_w,
    float* __restrict__ Vv, float* __restrict__ T, float* __restrict__ S,
    float* __restrict__ pooled)
{
    __shared__ float b1s[A_], b2s[A_], Ul[L_];
    const int tid = threadIdx.x, b = blockIdx.x;
    if (tid < A_) {
        float s1 = 0.f, s2 = 0.f;
        #pragma unroll
        for (int g = 0; g < H_; ++g) {
            s1 += Wx_w[g * 204 + 4 + tid];
            s2 += Wx_w[g * 204 + 104 + tid];
        }
        b1s[tid] = s1; b2s[tid] = s2;
        pooled[b * A_ + tid] = 0.f;
    }
    __syncthreads();
    for (int j = tid; j < L_; j += 256) {
        const float* xr = x1 + ((size_t)b * L_ + j) * XP_;
        float u = 0.f, v = 0.f;
        #pragma unroll 4
        for (int c = 0; c < A_; ++c) { float xv = xr[c]; u += xv * b1s[c]; v += xv * b2s[c]; }
        Ul[j] = u;
        Vv[b * L_ + j] = v;
    }
    __syncthreads();
    if (tid < A_) {
        float t = 0.f, s = 0.f;
        for (int j = 0; j < L_; ++j) {
            float xv = x1[((size_t)b * L_ + j) * XP_ + tid];
            t += xv; s += Ul[j] * xv;
        }
        T[b * A_ + tid] = t; S[b * A_ + tid] = s;
    }
}

// ---------------- K6: pooled[b] += sum_rows relu([x,x1,x2]@agg^T + b)   (tiled GEMM)
__global__ __launch_bounds__(256) void k_nodepool(
    const float* __restrict__ x, const float* __restrict__ x1, const float* __restrict__ x2,
    const float* __restrict__ aggT, const float* __restrict__ agg_b,
    float* __restrict__ pooled)
{
    __shared__ float ss[32][104];
    __shared__ float ws[A_][128];
    const int tid = threadIdx.x;
    const int row0 = blockIdx.x * 32;
    const int b = row0 >> 9;
    const int c4 = tid & 31, rg = tid >> 5;
    float4 acc[4];
    #pragma unroll
    for (int i = 0; i < 4; ++i) { acc[i].x = acc[i].y = acc[i].z = acc[i].w = 0.f; }

    for (int c = 0; c < 3; ++c) {
        const float* src = (c == 0) ? x : (c == 1) ? x1 : x2;
        for (int idx = tid; idx < 32 * 25; idx += 256) {
            const int r = idx / 25, k4 = idx % 25;
            *(float4*)&ss[r][k4 * 4] =
                *(const float4*)(src + (size_t)(row0 + r) * XP_ + k4 * 4);
        }
        for (int idx = tid; idx < A_ * 32; idx += 256) {
            const int k = idx >> 5, cc = idx & 31;
            *(float4*)&ws[k][cc * 4] =
                *(const float4*)(aggT + ((size_t)c * A_ + k) * 128 + cc * 4);
        }
        __syncthreads();
        #pragma unroll 5
        for (int k = 0; k < A_; k += 4) {
            float4 sv[4];
            #pragma unroll
            for (int i = 0; i < 4; ++i) sv[i] = *(float4*)&ss[rg * 4 + i][k];
            #pragma unroll
            for (int j = 0; j < 4; ++j) {
                float4 w4 = *(float4*)&ws[k + j][c4 * 4];
                #pragma unroll
                for (int i = 0; i < 4; ++i) {
                    const float sj = ((float*)&sv[i])[j];
                    acc[i].x += sj * w4.x; acc[i].y += sj * w4.y;
                    acc[i].z += sj * w4.z; acc[i].w += sj * w4.w;
                }
            }
        }
        __syncthreads();
    }

    float4 bias = {0.f, 0.f, 0.f, 0.f};
    if (c4 < 25) bias = ((const float4*)agg_b)[c4];
    float4 rs = {0.f, 0.f, 0.f, 0.f};
    #pragma unroll
    for (int i = 0; i < 4; ++i) {
        rs.x += fmaxf(acc[i].x + bias.x, 0.f);
        rs.y += fmaxf(acc[i].y + bias.y, 0.f);
        rs.z += fmaxf(acc[i].z + bias.z, 0.f);
        rs.w += fmaxf(acc[i].w + bias.w, 0.f);
    }
    float* red = &ss[0][0];
    __syncthreads();
    *(float4*)&red[rg * 128 + c4 * 4] = rs;
    __syncthreads();
    if (rg == 0 && c4 < 25) {
        float4 tot = {0.f, 0.f, 0.f, 0.f};
        #pragma unroll
        for (int g = 0; g < 8; ++g) {
            float4 v = *(float4*)&red[g * 128 + c4 * 4];
            tot.x += v.x; tot.y += v.y; tot.z += v.z; tot.w += v.w;
        }
        atomicAdd(&pooled[b * A_ + c4 * 4 + 0], tot.x);
        atomicAdd(&pooled[b * A_ + c4 * 4 + 1], tot.y);
        atomicAdd(&pooled[b * A_ + c4 * 4 + 2], tot.z);
        atomicAdd(&pooled[b * A_ + c4 * 4 + 3], tot.w);
    }
}

// ---------------- K7: logits = (pooled/valid_len) @ cls^T + b
__global__ __launch_bounds__(64) void k_logits(
    const float* __restrict__ pooled, const float* __restrict__ cls_w,
    const float* __restrict__ cls_b, const int* __restrict__ mask_ids,
    float* __restrict__ out)
{
    const int tid = threadIdx.x;
    if (tid < B_ * P_) {
        const int b = tid / P_, p = tid % P_;
        int vs = 0;
        for (int l = 0; l < L_; ++l) vs += mask_ids[b * L_ + l];
        float inv = 1.0f / (float)max(vs, 1);
        float acc = cls_b[p];
        #pragma unroll 4
        for (int a = 0; a < A_; ++a) acc += (pooled[b * A_ + a] * inv) * cls_w[p * A_ + a];
        out[b * P_ + p] = acc;
    }
}

extern "C" void kernel_launch(void* const* d_in, const int* in_sizes, int n_in,
                              void* d_out, int out_size, void* d_ws, size_t ws_size,
                              hipStream_t stream) {
    const float* seq    = (const float*)d_in[0];
    const float* syn    = (const float*)d_in[1];
    const float* ln_a   = (const float*)d_in[2];
    const float* ln_b   = (const float*)d_in[3];
    const float* Wxx_w  = (const float*)d_in[4];
    const float* Wxx_b  = (const float*)d_in[5];
    const float* q_w    = (const float*)d_in[6];
    const float* q_b    = (const float*)d_in[7];
    const float* k_w    = (const float*)d_in[8];
    const float* k_b    = (const float*)d_in[9];
    const float* W_w    = (const float*)d_in[10];
    const float* W_b    = (const float*)d_in[11];
    const float* Wx_w   = (const float*)d_in[12];
    const float* Wx_b   = (const float*)d_in[13];
    const float* agg_w  = (const float*)d_in[14];
    const float* agg_b  = (const float*)d_in[15];
    const float* cls_w  = (const float*)d_in[16];
    const float* cls_b  = (const float*)d_in[17];
    const int* mask_ids = (const int*)d_in[18];
    const int* src_mask = (const int*)d_in[19];
    float* out = (float*)d_out;

    float* ws = (float*)d_ws;
    size_t off = 0;
    float* xp     = ws + off; off += (size_t)B_ * L_ * XP_;
    float* x1p    = ws + off; off += (size_t)B_ * L_ * XP_;
    float* x2p    = ws + off; off += (size_t)B_ * L_ * XP_;
    float* axb    = ws + off; off += (size_t)B_ * L_ * XP_;
    float* qt     = ws + off; off += (size_t)B_ * L_ * A_;
    float* kt     = ws + off; off += (size_t)B_ * L_ * A_;
    float* es     = ws + off; off += (size_t)B_ * H_ * L_ * L_;
    float* Vv     = ws + off; off += (size_t)B_ * L_;
    float* T      = ws + off; off += (size_t)B_ * A_;
    float* S      = ws + off; off += (size_t)B_ * A_;
    float* pooled = ws + off; off += (size_t)B_ * A_;
    float* wT     = ws + off; off += (size_t)D_ * 128;
    float* aggT   = ws + off; off += (size_t)3 * A_ * 128;
    float* qkT    = ws + off; off += (size_t)A_ * 256;
    float* WT     = ws + off; off += (size_t)A_ * 128;
    float* colsum = ws + off; off += 128;
    float* basev  = ws + off; off += 128;

    k_wprep<<<(D_ * 128) / 256, 256, 0, stream>>>(Wxx_w, ln_a, wT);
    k_vecprep<<<1, 128, 0, stream>>>(Wxx_w, ln_a, ln_b, Wxx_b, colsum, basev);
    k_aggprep<<<(3 * A_ * 128) / 256, 256, 0, stream>>>(agg_w, aggT);
    k_qkprep<<<(A_ * 256) / 256, 256, 0, stream>>>(q_w, k_w, qkT);
    k_wprep2<<<(A_ * 128) / 256, 256, 0, stream>>>(W_w, WT);
    k_lnx<<<(B_ * L_) / 16, 128, 0, stream>>>(seq, wT, colsum, basev, xp);
    k_qkg<<<dim3((B_ * L_) / 32, 2), 256, 0, stream>>>(xp, qkT, q_b, k_b, qt, kt);
    k_sgemm<<<dim3(8, 8, B_ * H_), 256, 0, stream>>>(qt, kt, syn, src_mask, es);
    k_softmax<<<B_ * L_, 256, 0, stream>>>(Wx_w, es);
    k_axg<0><<<(B_ * L_) / 16, 128, 0, stream>>>(es, xp, nullptr, nullptr, nullptr, nullptr, axb);
    k_xw<<<(B_ * L_) / 16, 128, 0, stream>>>(axb, WT, W_b, x1p);
    k_extras<<<B_, 256, 0, stream>>>(x1p, Wx_w, Vv, T, S, pooled);
    k_axg<1><<<(B_ * L_) / 16, 128, 0, stream>>>(es + (size_t)L_ * L_, x1p, S, T, Vv, Wx_b, axb);
    k_xw<<<(B_ * L_) / 16, 128, 0, stream>>>(axb, WT, W_b, x2p);
    k_nodepool<<<(B_ * L_) / 32, 256, 0, stream>>>(xp, x1p, x2p, aggT, agg_b, pooled);
    k_logits<<<1, 64, 0, stream>>>(pooled, cls_w, cls_b, mask_ids, out);
}

// Round 9
// 404.582 us; speedup vs baseline: 1.1472x; 1.1472x over previous
//
#include <hip/hip_runtime.h>

#define B_ 16
#define L_ 512
#define D_ 768
#define H_ 4
#define A_ 100
#define DK_ 25
#define P_ 3
#define XP_ 128                  // padded row stride
#define PHALF_ (8192 * 128)      // one K-partial plane (B*L x XP)

// ------------------------------------------- K0: wT[d][a] = ln_a[d]*Wxx_w[a][d], pad a to 128
__global__ __launch_bounds__(256) void k_wprep(const float* __restrict__ Wxx_w,
                                               const float* __restrict__ ln_a,
                                               float* __restrict__ wT)
{
    const int idx = blockIdx.x * 256 + threadIdx.x;     // 768*128
    const int d = idx >> 7, a = idx & 127;
    wT[idx] = (a < A_) ? ln_a[d] * Wxx_w[(size_t)a * D_ + d] : 0.f;
}

// ---------------- K0e: colsum[a] = sum_d ln_a[d]*Wxx[a][d]; basev[a] = ln_b@Wxx^T + Wxx_b
__global__ __launch_bounds__(128) void k_vecprep(const float* __restrict__ Wxx_w,
                                                 const float* __restrict__ ln_a,
                                                 const float* __restrict__ ln_b,
                                                 const float* __restrict__ Wxx_b,
                                                 float* __restrict__ colsum,
                                                 float* __restrict__ basev)
{
    const int a = threadIdx.x;
    float cs = 0.f, bs = 0.f;
    if (a < A_) {
        const float* wr = Wxx_w + (size_t)a * D_;
        for (int d = 0; d < D_; ++d) {
            const float w = wr[d];
            cs += ln_a[d] * w;
            bs += ln_b[d] * w;
        }
        bs += Wxx_b[a];
    }
    colsum[a] = (a < A_) ? cs : 0.f;
    basev[a]  = (a < A_) ? bs : 0.f;
}

// ------------------------------------- K0b: aggT[c][k][n] = agg_w[n][c*100+k], pad n to 128
__global__ __launch_bounds__(256) void k_aggprep(const float* __restrict__ agg_w,
                                                 float* __restrict__ aggT)
{
    const int idx = blockIdx.x * 256 + threadIdx.x;     // 3*100*128
    const int n = idx & 127, k = (idx >> 7) % A_, c = idx / (128 * A_);
    aggT[idx] = (n < A_) ? agg_w[(size_t)n * (3 * A_) + c * A_ + k] : 0.f;
}

// --------------------- K0c: qkT[k][n]: n<128 -> q_w[n][k], n>=128 -> k_w[n-128][k]
__global__ __launch_bounds__(256) void k_qkprep(const float* __restrict__ q_w,
                                                const float* __restrict__ k_w,
                                                float* __restrict__ qkT)
{
    const int idx = blockIdx.x * 256 + threadIdx.x;     // 100*256
    const int n = idx & 255, k = idx >> 8;
    const int half = n >> 7, a = n & 127;
    const float* w = half ? k_w : q_w;
    qkT[idx] = (a < A_) ? w[(size_t)a * A_ + k] : 0.f;
}

// ------------------------------------- K0d: WT[k][n] = W_w[n][k], pad n to 128
__global__ __launch_bounds__(256) void k_wprep2(const float* __restrict__ W_w,
                                                float* __restrict__ WT)
{
    const int idx = blockIdx.x * 256 + threadIdx.x;     // 100*128
    const int n = idx & 127, k = idx >> 7;
    WT[idx] = (n < A_) ? W_w[(size_t)n * A_ + k] : 0.f;
}

// ------------------- K1a: K-split partial of seq@W2 + partial LN stats
// grid (256, 2): x = 32-row tile, y = K half (384 each). 256 threads, 4x4 reg tile.
__global__ __launch_bounds__(256) void k_lnx(
    const float* __restrict__ seq, const float* __restrict__ wT,
    float* __restrict__ part, float2* __restrict__ statp)
{
    __shared__ float ss[32][36];        // raw seq chunk, +4 pad
    __shared__ float ws[32][128];
    const int tid = threadIdx.x;
    const int row0 = blockIdx.x * 32;
    const int kz = blockIdx.y;          // K half
    const int kbase = kz * 12;          // chunk offset (12 chunks of 32)
    const int c4 = tid & 31, rg = tid >> 5;

    float4 acc[4];
    float rsum[4] = {0.f, 0.f, 0.f, 0.f};
    float rsq[4]  = {0.f, 0.f, 0.f, 0.f};
    #pragma unroll
    for (int i = 0; i < 4; ++i) { acc[i].x = acc[i].y = acc[i].z = acc[i].w = 0.f; }

    for (int kc = 0; kc < 12; ++kc) {
        {   // stage raw seq chunk: 32 rows x 32 k = 256 float4, 1/thread
            const int r = tid >> 3, k4 = tid & 7;
            *(float4*)&ss[r][k4 * 4] =
                *(const float4*)(seq + (size_t)(row0 + r) * D_ + (kbase + kc) * 32 + k4 * 4);
        }
        #pragma unroll
        for (int t = 0; t < 4; ++t) {   // stage weight chunk: 1024 float4, 4/thread
            const int idx = tid + t * 256;
            const int k = idx >> 5, cc = idx & 31;
            *(float4*)&ws[k][cc * 4] =
                *(const float4*)(wT + (size_t)(kbase + kc) * 4096 + (size_t)k * 128 + cc * 4);
        }
        __syncthreads();
        #pragma unroll 2
        for (int k = 0; k < 32; k += 4) {
            float4 sv[4];
            #pragma unroll
            for (int i = 0; i < 4; ++i) {
                sv[i] = *(float4*)&ss[rg * 4 + i][k];
                rsum[i] += sv[i].x + sv[i].y + sv[i].z + sv[i].w;
                rsq[i]  += sv[i].x * sv[i].x + sv[i].y * sv[i].y
                         + sv[i].z * sv[i].z + sv[i].w * sv[i].w;
            }
            #pragma unroll
            for (int j = 0; j < 4; ++j) {
                float4 w4 = *(float4*)&ws[k + j][c4 * 4];
                #pragma unroll
                for (int i = 0; i < 4; ++i) {
                    const float sj = ((float*)&sv[i])[j];
                    acc[i].x += sj * w4.x; acc[i].y += sj * w4.y;
                    acc[i].z += sj * w4.z; acc[i].w += sj * w4.w;
                }
            }
        }
        __syncthreads();
    }

    float* dst = part + (size_t)kz * PHALF_;
    #pragma unroll
    for (int i = 0; i < 4; ++i) {
        const int grow = row0 + rg * 4 + i;
        *(float4*)(dst + (size_t)grow * XP_ + c4 * 4) = acc[i];
        if (c4 == 0) statp[(size_t)kz * 8192 + grow] = make_float2(rsum[i], rsq[i]);
    }
}

// ------------------- K1b: combine partials + LN epilogue -> xp (8 rows/block)
__global__ __launch_bounds__(256) void k_lnfin(
    const float* __restrict__ part, const float2* __restrict__ statp,
    const float* __restrict__ colsum, const float* __restrict__ basev,
    float* __restrict__ xp)
{
    const int tid = threadIdx.x;
    const int row = blockIdx.x * 8 + (tid >> 5);
    const int c4 = tid & 31;
    const float2 s0 = statp[row], s1 = statp[8192 + row];
    const float m = (s0.x + s1.x) * (1.0f / 768.0f);
    const float var = ((s0.y + s1.y) - 768.0f * m * m) * (1.0f / 767.0f);  // ddof=1
    const float rd = 1.0f / (sqrtf(var) + 1e-6f);                           // std + EPS
    float4 p0 = *(const float4*)(part + (size_t)row * XP_ + c4 * 4);
    float4 p1 = *(const float4*)(part + PHALF_ + (size_t)row * XP_ + c4 * 4);
    const float4 cs4 = ((const float4*)colsum)[c4];
    const float4 bs4 = ((const float4*)basev)[c4];
    float4 o;
    o.x = rd * (p0.x + p1.x - m * cs4.x) + bs4.x;
    o.y = rd * (p0.y + p1.y - m * cs4.y) + bs4.y;
    o.z = rd * (p0.z + p1.z - m * cs4.z) + bs4.z;
    o.w = rd * (p0.w + p1.w - m * cs4.w) + bs4.w;
    *(float4*)(xp + (size_t)row * XP_ + c4 * 4) = o;   // pad cols stay 0 (wT/colsum/basev padded)
}

// ------------------- K2: q/k = x @ [q_w|k_w]^T + bias  (tiled GEMM); qt/kt (B,L,100)
__global__ __launch_bounds__(256) void k_qkg(
    const float* __restrict__ xp, const float* __restrict__ qkT,
    const float* __restrict__ q_b, const float* __restrict__ k_b,
    float* __restrict__ qt, float* __restrict__ kt)
{
    __shared__ float ss[32][104];
    __shared__ float ws[A_][128];
    const int tid = threadIdx.x;
    const int row0 = blockIdx.x * 32;
    const int half = blockIdx.y;
    const int c4 = tid & 31, rg = tid >> 5;

    for (int idx = tid; idx < 32 * 25; idx += 256) {
        const int r = idx / 25, k4 = idx % 25;
        *(float4*)&ss[r][k4 * 4] = *(const float4*)(xp + (size_t)(row0 + r) * XP_ + k4 * 4);
    }
    for (int idx = tid; idx < A_ * 32; idx += 256) {
        const int k = idx >> 5, cc = idx & 31;
        *(float4*)&ws[k][cc * 4] = *(const float4*)(qkT + (size_t)k * 256 + half * 128 + cc * 4);
    }
    __syncthreads();

    float4 acc[4];
    #pragma unroll
    for (int i = 0; i < 4; ++i) { acc[i].x = acc[i].y = acc[i].z = acc[i].w = 0.f; }
    #pragma unroll 5
    for (int k = 0; k < A_; k += 4) {
        float4 sv[4];
        #pragma unroll
        for (int i = 0; i < 4; ++i) sv[i] = *(float4*)&ss[rg * 4 + i][k];
        #pragma unroll
        for (int j = 0; j < 4; ++j) {
            float4 w4 = *(float4*)&ws[k + j][c4 * 4];
            #pragma unroll
            for (int i = 0; i < 4; ++i) {
                const float sj = ((float*)&sv[i])[j];
                acc[i].x += sj * w4.x; acc[i].y += sj * w4.y;
                acc[i].z += sj * w4.z; acc[i].w += sj * w4.w;
            }
        }
    }

    if (c4 < 25) {
        const float4 bias = ((const float4*)(half ? k_b : q_b))[c4];
        float* dst = half ? kt : qt;
        #pragma unroll
        for (int i = 0; i < 4; ++i) {
            float4 o;
            o.x = acc[i].x + bias.x; o.y = acc[i].y + bias.y;
            o.z = acc[i].z + bias.z; o.w = acc[i].w + bias.w;
            *(float4*)(dst + (size_t)(row0 + rg * 4 + i) * A_ + c4 * 4) = o;
        }
    }
}

// --------------- K3a: es[bh][i][j] = (mask? q.k/5 : -1e9) + syn   (64x64 tile GEMM, K=25)
__global__ __launch_bounds__(256) void k_sgemm(
    const float* __restrict__ qt, const float* __restrict__ kt,
    const float* __restrict__ syn, const int* __restrict__ src_mask,
    float* __restrict__ es)
{
    __shared__ float qs[DK_][64];
    __shared__ float ks[DK_][64];
    __shared__ int ms[64];
    const int tid = threadIdx.x;
    const int bh = blockIdx.z;
    const int b = bh >> 2, h = bh & 3;
    const int i0 = blockIdx.x * 64, j0 = blockIdx.y * 64;
    const float* qbase = qt + ((size_t)b * L_ + i0) * A_ + h * DK_;
    const float* kbase = kt + ((size_t)b * L_ + j0) * A_ + h * DK_;
    {
        const int r = tid >> 2, c = tid & 3;
        #pragma unroll
        for (int k = 0; k < 7; ++k) {
            const int d = c + 4 * k;
            if (d < DK_) {
                qs[d][r] = qbase[(size_t)r * A_ + d];
                ks[d][r] = kbase[(size_t)r * A_ + d];
            }
        }
        if (tid < 64) ms[tid] = src_mask[b * L_ + j0 + tid];
    }
    __syncthreads();
    const int ty = tid >> 4, tx = tid & 15;
    float acc[4][4] = {};
    #pragma unroll 5
    for (int d = 0; d < DK_; ++d) {
        float4 qv = *(const float4*)&qs[d][ty * 4];
        float4 kv = *(const float4*)&ks[d][tx * 4];
        const float q[4] = {qv.x, qv.y, qv.z, qv.w};
        const float kk[4] = {kv.x, kv.y, kv.z, kv.w};
        #pragma unroll
        for (int ii = 0; ii < 4; ++ii)
            #pragma unroll
            for (int jj = 0; jj < 4; ++jj)
                acc[ii][jj] += q[ii] * kk[jj];
    }
    const int irow = i0 + ty * 4, jcol = j0 + tx * 4;
    const int m0 = ms[tx * 4], m1 = ms[tx * 4 + 1], m2 = ms[tx * 4 + 2], m3 = ms[tx * 4 + 3];
    #pragma unroll
    for (int ii = 0; ii < 4; ++ii) {
        const size_t o = ((size_t)bh * L_ + irow + ii) * L_ + jcol;
        float4 sv = *(const float4*)(syn + o);
        float4 w;
        w.x = (m0 ? acc[ii][0] * 0.2f : -1e9f) + sv.x;
        w.y = (m1 ? acc[ii][1] * 0.2f : -1e9f) + sv.y;
        w.z = (m2 ? acc[ii][2] * 0.2f : -1e9f) + sv.z;
        w.w = (m3 ? acc[ii][3] * 0.2f : -1e9f) + sv.w;
        *(float4*)(es + o) = w;
    }
}

// --------------- K3b: softmax over j per (b,h,i); adjsum -> es plane0, wadj -> plane1
__global__ __launch_bounds__(256) void k_softmax(
    const float* __restrict__ Wx_w, float* __restrict__ es)
{
    __shared__ float ps[H_][L_];
    __shared__ float cs[H_];
    const int tid = threadIdx.x, r = blockIdx.x;
    const int b = r >> 9, i = r & 511;
    const int h = tid >> 6, lane = tid & 63;
    if (tid < H_) cs[tid] = Wx_w[tid] + Wx_w[204 + tid] + Wx_w[408 + tid] + Wx_w[612 + tid];
    float* row = es + (((size_t)(b * H_ + h)) * L_ + i) * L_;
    float4 v0 = ((const float4*)row)[lane];
    float4 v1 = ((const float4*)row)[lane + 64];
    float mx = fmaxf(fmaxf(fmaxf(v0.x, v0.y), fmaxf(v0.z, v0.w)),
                     fmaxf(fmaxf(v1.x, v1.y), fmaxf(v1.z, v1.w)));
    #pragma unroll
    for (int o = 32; o; o >>= 1) mx = fmaxf(mx, __shfl_xor(mx, o));
    float4 e0, e1;
    e0.x = __expf(v0.x - mx); e0.y = __expf(v0.y - mx);
    e0.z = __expf(v0.z - mx); e0.w = __expf(v0.w - mx);
    e1.x = __expf(v1.x - mx); e1.y = __expf(v1.y - mx);
    e1.z = __expf(v1.z - mx); e1.w = __expf(v1.w - mx);
    float sum = e0.x + e0.y + e0.z + e0.w + e1.x + e1.y + e1.z + e1.w;
    #pragma unroll
    for (int o = 32; o; o >>= 1) sum += __shfl_xor(sum, o);
    const float inv = 1.0f / sum;
    e0.x *= inv; e0.y *= inv; e0.z *= inv; e0.w *= inv;
    e1.x *= inv; e1.y *= inv; e1.z *= inv; e1.w *= inv;
    *(float4*)&ps[h][lane * 4] = e0;
    *(float4*)&ps[h][(lane + 64) * 4] = e1;
    __syncthreads();
    float* arow = es + (((size_t)(b * H_ + 0)) * L_ + i) * L_;
    float* wrow = es + (((size_t)(b * H_ + 1)) * L_ + i) * L_;
    const int t = tid & 127;
    float4 p0 = *(float4*)&ps[0][t * 4];
    float4 p1 = *(float4*)&ps[1][t * 4];
    float4 p2 = *(float4*)&ps[2][t * 4];
    float4 p3 = *(float4*)&ps[3][t * 4];
    if (tid < 128) {
        float4 o;
        o.x = p0.x + p1.x + p2.x + p3.x;
        o.y = p0.y + p1.y + p2.y + p3.y;
        o.z = p0.z + p1.z + p2.z + p3.z;
        o.w = p0.w + p1.w + p2.w + p3.w;
        *(float4*)(arow + t * 4) = o;
    } else {
        const float c0 = cs[0], c1 = cs[1], c2 = cs[2], c3 = cs[3];
        float4 o;
        o.x = c0 * p0.x + c1 * p1.x + c2 * p2.x + c3 * p3.x;
        o.y = c0 * p0.y + c1 * p1.y + c2 * p2.y + c3 * p3.y;
        o.z = c0 * p0.z + c1 * p1.z + c2 * p2.z + c3 * p3.z;
        o.w = c0 * p0.w + c1 * p1.w + c2 * p2.w + c3 * p3.w;
        *(float4*)(wrow + t * 4) = o;
    }
}

// ------------- K4a: partial adj@x over K half; grid (256, 2), 256 thr, 32-row tile
__global__ __launch_bounds__(256) void k_axp(
    const float* __restrict__ adj, const float* __restrict__ xp,
    float* __restrict__ part)
{
    __shared__ float ss[32][36];        // adj chunk, +4 pad
    __shared__ float ws[32][128];       // x chunk
    const int tid = threadIdx.x;
    const int row0 = blockIdx.x * 32;       // global row in [0, B*L)
    const int kz = blockIdx.y;              // K half (256 each)
    const int b = row0 >> 9, i0 = row0 & 511;
    const float* adjb = adj + (size_t)b * 4 * L_ * L_;
    const float* xpb = xp + (size_t)b * L_ * XP_ + (size_t)kz * 256 * XP_;
    const int c4 = tid & 31, rg = tid >> 5;
    float4 acc[4];
    #pragma unroll
    for (int i = 0; i < 4; ++i) { acc[i].x = acc[i].y = acc[i].z = acc[i].w = 0.f; }

    for (int kc = 0; kc < 8; ++kc) {
        {
            const int r = tid >> 3, k4 = tid & 7;
            *(float4*)&ss[r][k4 * 4] =
                *(const float4*)(adjb + (size_t)(i0 + r) * L_ + kz * 256 + kc * 32 + k4 * 4);
        }
        #pragma unroll
        for (int t = 0; t < 4; ++t) {
            const int idx = tid + t * 256;
            const int k = idx >> 5, cc = idx & 31;
            *(float4*)&ws[k][cc * 4] =
                *(const float4*)(xpb + (size_t)(kc * 32 + k) * XP_ + cc * 4);
        }
        __syncthreads();
        #pragma unroll 2
        for (int k = 0; k < 32; k += 4) {
            float4 sv[4];
            #pragma unroll
            for (int i = 0; i < 4; ++i) sv[i] = *(float4*)&ss[rg * 4 + i][k];
            #pragma unroll
            for (int j = 0; j < 4; ++j) {
                float4 w4 = *(float4*)&ws[k + j][c4 * 4];
                #pragma unroll
                for (int i = 0; i < 4; ++i) {
                    const float sj = ((float*)&sv[i])[j];
                    acc[i].x += sj * w4.x; acc[i].y += sj * w4.y;
                    acc[i].z += sj * w4.z; acc[i].w += sj * w4.w;
                }
            }
        }
        __syncthreads();
    }

    float* dst = part + (size_t)kz * PHALF_;
    #pragma unroll
    for (int i = 0; i < 4; ++i)
        *(float4*)(dst + (size_t)(row0 + rg * 4 + i) * XP_ + c4 * 4) = acc[i];
}

// ------------- K4b: xout = relu(((p0+p1)/H [+extras]) @ W^T + b)   (combine in staging)
template<int LAYER2>
__global__ __launch_bounds__(256) void k_xw(
    const float* __restrict__ part, const float* __restrict__ WT,
    const float* __restrict__ W_b, const float* __restrict__ S,
    const float* __restrict__ T, const float* __restrict__ Vv,
    const float* __restrict__ Wx_b, float* __restrict__ xout)
{
    __shared__ float ss[32][104];
    __shared__ float ws[A_][128];
    const int tid = threadIdx.x;
    const int row0 = blockIdx.x * 32;
    const int b = row0 >> 9;
    const int c4 = tid & 31, rg = tid >> 5;

    float wb = 0.f;
    if (LAYER2) wb = Wx_b[0] + Wx_b[1] + Wx_b[2] + Wx_b[3];

    for (int idx = tid; idx < 32 * 25; idx += 256) {
        const int r = idx / 25, k4 = idx % 25;
        const int grow = row0 + r;
        float4 a0 = *(const float4*)(part + (size_t)grow * XP_ + k4 * 4);
        float4 a1 = *(const float4*)(part + PHALF_ + (size_t)grow * XP_ + k4 * 4);
        float4 v;
        if (LAYER2) {
            const float4 s4 = *(const float4*)(S + b * A_ + k4 * 4);
            const float4 t4 = *(const float4*)(T + b * A_ + k4 * 4);
            const float vv = Vv[grow] + wb;
            v.x = (a0.x + a1.x + s4.x + vv * t4.x) * 0.25f;
            v.y = (a0.y + a1.y + s4.y + vv * t4.y) * 0.25f;
            v.z = (a0.z + a1.z + s4.z + vv * t4.z) * 0.25f;
            v.w = (a0.w + a1.w + s4.w + vv * t4.w) * 0.25f;
        } else {
            v.x = (a0.x + a1.x) * 0.25f;
            v.y = (a0.y + a1.y) * 0.25f;
            v.z = (a0.z + a1.z) * 0.25f;
            v.w = (a0.w + a1.w) * 0.25f;
        }
        *(float4*)&ss[r][k4 * 4] = v;
    }
    for (int idx = tid; idx < A_ * 32; idx += 256) {
        const int k = idx >> 5, cc = idx & 31;
        *(float4*)&ws[k][cc * 4] = *(const float4*)(WT + (size_t)k * 128 + cc * 4);
    }
    __syncthreads();

    float4 acc[4];
    #pragma unroll
    for (int i = 0; i < 4; ++i) { acc[i].x = acc[i].y = acc[i].z = acc[i].w = 0.f; }
    #pragma unroll 5
    for (int k = 0; k < A_; k += 4) {
        float4 sv[4];
        #pragma unroll
        for (int i = 0; i < 4; ++i) sv[i] = *(float4*)&ss[rg * 4 + i][k];
        #pragma unroll
        for (int j = 0; j < 4; ++j) {
            float4 w4 = *(float4*)&ws[k + j][c4 * 4];
            #pragma unroll
            for (int i = 0; i < 4; ++i) {
                const float sj = ((float*)&sv[i])[j];
                acc[i].x += sj * w4.x; acc[i].y += sj * w4.y;
                acc[i].z += sj * w4.z; acc[i].w += sj * w4.w;
            }
        }
    }

    float4 bias = {0.f, 0.f, 0.f, 0.f};
    if (c4 < 25) bias = ((const float4*)W_b)[c4];
    #pragma unroll
    for (int i = 0; i < 4; ++i) {
        float4 o;
        o.x = fmaxf(acc[i].x + bias.x, 0.f); o.y = fmaxf(acc[i].y + bias.y, 0.f);
        o.z = fmaxf(acc[i].z + bias.z, 0.f); o.w = fmaxf(acc[i].w + bias.w, 0.f);
        *(float4*)(xout + (size_t)(row0 + rg * 4 + i) * XP_ + c4 * 4) = o;  // WT pad -> 0
    }
}

// ---------------- K5: rank-1 extras for layer 2: Vv (B,L), T,S (B,A); zero pooled
__global__ __launch_bounds__(256) void k_extras(
    const float* __restrict__ x1, const float* __restrict__ Wx_w,
    float* __restrict__ Vv, float* __restrict__ T, float* __restrict__ S,
    float* __restrict__ pooled)
{
    __shared__ float b1s[A_], b2s[A_], Ul[L_];
    const int tid = threadIdx.x, b = blockIdx.x;
    if (tid < A_) {
        float s1 = 0.f, s2 = 0.f;
        #pragma unroll
        for (int g = 0; g < H_; ++g) {
            s1 += Wx_w[g * 204 + 4 + tid];
            s2 += Wx_w[g * 204 + 104 + tid];
        }
        b1s[tid] = s1; b2s[tid] = s2;
        pooled[b * A_ + tid] = 0.f;
    }
    __syncthreads();
    for (int j = tid; j < L_; j += 256) {
        const float* xr = x1 + ((size_t)b * L_ + j) * XP_;
        float u = 0.f, v = 0.f;
        #pragma unroll 4
        for (int c = 0; c < A_; ++c) { float xv = xr[c]; u += xv * b1s[c]; v += xv * b2s[c]; }
        Ul[j] = u;
        Vv[b * L_ + j] = v;
    }
    __syncthreads();
    if (tid < A_) {
        float t = 0.f, s = 0.f;
        for (int j = 0; j < L_; ++j) {
            float xv = x1[((size_t)b * L_ + j) * XP_ + tid];
            t += xv; s += Ul[j] * xv;
        }
        T[b * A_ + tid] = t; S[b * A_ + tid] = s;
    }
}

// ---------------- K6: pooled[b] += sum_rows relu([x,x1,x2]@agg^T + b)   (tiled GEMM)
__global__ __launch_bounds__(256) void k_nodepool(
    const float* __restrict__ x, const float* __restrict__ x1, const float* __restrict__ x2,
    const float* __restrict__ aggT, const float* __restrict__ agg_b,
    float* __restrict__ pooled)
{
    __shared__ float ss[32][104];
    __shared__ float ws[A_][128];
    const int tid = threadIdx.x;
    const int row0 = blockIdx.x * 32;
    const int b = row0 >> 9;
    const int c4 = tid & 31, rg = tid >> 5;
    float4 acc[4];
    #pragma unroll
    for (int i = 0; i < 4; ++i) { acc[i].x = acc[i].y = acc[i].z = acc[i].w = 0.f; }

    for (int c = 0; c < 3; ++c) {
        const float* src = (c == 0) ? x : (c == 1) ? x1 : x2;
        for (int idx = tid; idx < 32 * 25; idx += 256) {
            const int r = idx / 25, k4 = idx % 25;
            *(float4*)&ss[r][k4 * 4] =
                *(const float4*)(src + (size_t)(row0 + r) * XP_ + k4 * 4);
        }
        for (int idx = tid; idx < A_ * 32; idx += 256) {
            const int k = idx >> 5, cc = idx & 31;
            *(float4*)&ws[k][cc * 4] =
                *(const float4*)(aggT + ((size_t)c * A_ + k) * 128 + cc * 4);
        }
        __syncthreads();
        #pragma unroll 5
        for (int k = 0; k < A_; k += 4) {
            float4 sv[4];
            #pragma unroll
            for (int i = 0; i < 4; ++i) sv[i] = *(float4*)&ss[rg * 4 + i][k];
            #pragma unroll
            for (int j = 0; j < 4; ++j) {
                float4 w4 = *(float4*)&ws[k + j][c4 * 4];
                #pragma unroll
                for (int i = 0; i < 4; ++i) {
                    const float sj = ((float*)&sv[i])[j];
                    acc[i].x += sj * w4.x; acc[i].y += sj * w4.y;
                    acc[i].z += sj * w4.z; acc[i].w += sj * w4.w;
                }
            }
        }
        __syncthreads();
    }

    float4 bias = {0.f, 0.f, 0.f, 0.f};
    if (c4 < 25) bias = ((const float4*)agg_b)[c4];
    float4 rs = {0.f, 0.f, 0.f, 0.f};
    #pragma unroll
    for (int i = 0; i < 4; ++i) {
        rs.x += fmaxf(acc[i].x + bias.x, 0.f);
        rs.y += fmaxf(acc[i].y + bias.y, 0.f);
        rs.z += fmaxf(acc[i].z + bias.z, 0.f);
        rs.w += fmaxf(acc[i].w + bias.w, 0.f);
    }
    float* red = &ss[0][0];
    __syncthreads();
    *(float4*)&red[rg * 128 + c4 * 4] = rs;
    __syncthreads();
    if (rg == 0 && c4 < 25) {
        float4 tot = {0.f, 0.f, 0.f, 0.f};
        #pragma unroll
        for (int g = 0; g < 8; ++g) {
            float4 v = *(float4*)&red[g * 128 + c4 * 4];
            tot.x += v.x; tot.y += v.y; tot.z += v.z; tot.w += v.w;
        }
        atomicAdd(&pooled[b * A_ + c4 * 4 + 0], tot.x);
        atomicAdd(&pooled[b * A_ + c4 * 4 + 1], tot.y);
        atomicAdd(&pooled[b * A_ + c4 * 4 + 2], tot.z);
        atomicAdd(&pooled[b * A_ + c4 * 4 + 3], tot.w);
    }
}

// ---------------- K7: logits = (pooled/valid_len) @ cls^T + b
__global__ __launch_bounds__(64) void k_logits(
    const float* __restrict__ pooled, const float* __restrict__ cls_w,
    const float* __restrict__ cls_b, const int* __restrict__ mask_ids,
    float* __restrict__ out)
{
    const int tid = threadIdx.x;
    if (tid < B_ * P_) {
        const int b = tid / P_, p = tid % P_;
        int vs = 0;
        for (int l = 0; l < L_; ++l) vs += mask_ids[b * L_ + l];
        float inv = 1.0f / (float)max(vs, 1);
        float acc = cls_b[p];
        #pragma unroll 4
        for (int a = 0; a < A_; ++a) acc += (pooled[b * A_ + a] * inv) * cls_w[p * A_ + a];
        out[b * P_ + p] = acc;
    }
}

extern "C" void kernel_launch(void* const* d_in, const int* in_sizes, int n_in,
                              void* d_out, int out_size, void* d_ws, size_t ws_size,
                              hipStream_t stream) {
    const float* seq    = (const float*)d_in[0];
    const float* syn    = (const float*)d_in[1];
    const float* ln_a   = (const float*)d_in[2];
    const float* ln_b   = (const float*)d_in[3];
    const float* Wxx_w  = (const float*)d_in[4];
    const float* Wxx_b  = (const float*)d_in[5];
    const float* q_w    = (const float*)d_in[6];
    const float* q_b    = (const float*)d_in[7];
    const float* k_w    = (const float*)d_in[8];
    const float* k_b    = (const float*)d_in[9];
    const float* W_w    = (const float*)d_in[10];
    const float* W_b    = (const float*)d_in[11];
    const float* Wx_w   = (const float*)d_in[12];
    const float* Wx_b   = (const float*)d_in[13];
    const float* agg_w  = (const float*)d_in[14];
    const float* agg_b  = (const float*)d_in[15];
    const float* cls_w  = (const float*)d_in[16];
    const float* cls_b  = (const float*)d_in[17];
    const int* mask_ids = (const int*)d_in[18];
    const int* src_mask = (const int*)d_in[19];
    float* out = (float*)d_out;

    float* ws = (float*)d_ws;
    size_t off = 0;
    float* xp     = ws + off; off += (size_t)B_ * L_ * XP_;
    float* x1p    = ws + off; off += (size_t)B_ * L_ * XP_;
    float* x2p    = ws + off; off += (size_t)B_ * L_ * XP_;
    float* part   = ws + off; off += (size_t)2 * PHALF_;     // shared by lnx & axp phases
    float* qt     = ws + off; off += (size_t)B_ * L_ * A_;
    float* kt     = ws + off; off += (size_t)B_ * L_ * A_;
    float* es     = ws + off; off += (size_t)B_ * H_ * L_ * L_;
    float* Vv     = ws + off; off += (size_t)B_ * L_;
    float* T      = ws + off; off += (size_t)B_ * A_;
    float* S      = ws + off; off += (size_t)B_ * A_;
    float* pooled = ws + off; off += (size_t)B_ * A_;
    float* wT     = ws + off; off += (size_t)D_ * 128;
    float* aggT   = ws + off; off += (size_t)3 * A_ * 128;
    float* qkT    = ws + off; off += (size_t)A_ * 256;
    float* WT     = ws + off; off += (size_t)A_ * 128;
    float* colsum = ws + off; off += 128;
    float* basev  = ws + off; off += 128;
    float2* statp = (float2*)(ws + off); off += 2 * 8192 * 2;

    k_wprep<<<(D_ * 128) / 256, 256, 0, stream>>>(Wxx_w, ln_a, wT);
    k_vecprep<<<1, 128, 0, stream>>>(Wxx_w, ln_a, ln_b, Wxx_b, colsum, basev);
    k_aggprep<<<(3 * A_ * 128) / 256, 256, 0, stream>>>(agg_w, aggT);
    k_qkprep<<<(A_ * 256) / 256, 256, 0, stream>>>(q_w, k_w, qkT);
    k_wprep2<<<(A_ * 128) / 256, 256, 0, stream>>>(W_w, WT);
    k_lnx<<<dim3((B_ * L_) / 32, 2), 256, 0, stream>>>(seq, wT, part, statp);
    k_lnfin<<<(B_ * L_) / 8, 256, 0, stream>>>(part, statp, colsum, basev, xp);
    k_qkg<<<dim3((B_ * L_) / 32, 2), 256, 0, stream>>>(xp, qkT, q_b, k_b, qt, kt);
    k_sgemm<<<dim3(8, 8, B_ * H_), 256, 0, stream>>>(qt, kt, syn, src_mask, es);
    k_softmax<<<B_ * L_, 256, 0, stream>>>(Wx_w, es);
    k_axp<<<dim3((B_ * L_) / 32, 2), 256, 0, stream>>>(es, xp, part);
    k_xw<0><<<(B_ * L_) / 32, 256, 0, stream>>>(part, WT, W_b,
                                                nullptr, nullptr, nullptr, nullptr, x1p);
    k_extras<<<B_, 256, 0, stream>>>(x1p, Wx_w, Vv, T, S, pooled);
    k_axp<<<dim3((B_ * L_) / 32, 2), 256, 0, stream>>>(es + (size_t)L_ * L_, x1p, part);
    k_xw<1><<<(B_ * L_) / 32, 256, 0, stream>>>(part, WT, W_b, S, T, Vv, Wx_b, x2p);
    k_nodepool<<<(B_ * L_) / 32, 256, 0, stream>>>(xp, x1p, x2p, aggT, agg_b, pooled);
    k_logits<<<1, 64, 0, stream>>>(pooled, cls_w, cls_b, mask_ids, out);
}

// Round 10
// 402.493 us; speedup vs baseline: 1.1532x; 1.0052x over previous
//
#include <hip/hip_runtime.h>

#define B_ 16
#define L_ 512
#define D_ 768
#define H_ 4
#define A_ 100
#define DK_ 25
#define P_ 3
#define XP_ 128                  // padded row stride
#define PHALF_ (8192 * 128)      // one K-partial plane (B*L x XP)

// ------------------------------------------- K0: wT[d][a] = ln_a[d]*Wxx_w[a][d], pad a to 128
__global__ __launch_bounds__(256) void k_wprep(const float* __restrict__ Wxx_w,
                                               const float* __restrict__ ln_a,
                                               float* __restrict__ wT)
{
    const int idx = blockIdx.x * 256 + threadIdx.x;     // 768*128
    const int d = idx >> 7, a = idx & 127;
    wT[idx] = (a < A_) ? ln_a[d] * Wxx_w[(size_t)a * D_ + d] : 0.f;
}

// ---------------- K0e: colsum[a] = sum_d ln_a[d]*Wxx[a][d]; basev[a] = ln_b@Wxx^T + Wxx_b
__global__ __launch_bounds__(128) void k_vecprep(const float* __restrict__ Wxx_w,
                                                 const float* __restrict__ ln_a,
                                                 const float* __restrict__ ln_b,
                                                 const float* __restrict__ Wxx_b,
                                                 float* __restrict__ colsum,
                                                 float* __restrict__ basev)
{
    const int a = threadIdx.x;
    float cs = 0.f, bs = 0.f;
    if (a < A_) {
        const float* wr = Wxx_w + (size_t)a * D_;
        for (int d = 0; d < D_; ++d) {
            const float w = wr[d];
            cs += ln_a[d] * w;
            bs += ln_b[d] * w;
        }
        bs += Wxx_b[a];
    }
    colsum[a] = (a < A_) ? cs : 0.f;
    basev[a]  = (a < A_) ? bs : 0.f;
}

// ------------------------------------- K0b: aggT[c][k][n] = agg_w[n][c*100+k], pad n to 128
__global__ __launch_bounds__(256) void k_aggprep(const float* __restrict__ agg_w,
                                                 float* __restrict__ aggT)
{
    const int idx = blockIdx.x * 256 + threadIdx.x;     // 3*100*128
    const int n = idx & 127, k = (idx >> 7) % A_, c = idx / (128 * A_);
    aggT[idx] = (n < A_) ? agg_w[(size_t)n * (3 * A_) + c * A_ + k] : 0.f;
}

// --------------------- K0c: qkT[k][n]: n<128 -> q_w[n][k], n>=128 -> k_w[n-128][k]
__global__ __launch_bounds__(256) void k_qkprep(const float* __restrict__ q_w,
                                                const float* __restrict__ k_w,
                                                float* __restrict__ qkT)
{
    const int idx = blockIdx.x * 256 + threadIdx.x;     // 100*256
    const int n = idx & 255, k = idx >> 8;
    const int half = n >> 7, a = n & 127;
    const float* w = half ? k_w : q_w;
    qkT[idx] = (a < A_) ? w[(size_t)a * A_ + k] : 0.f;
}

// ------------------------------------- K0d: WT[k][n] = W_w[n][k], pad n to 128
__global__ __launch_bounds__(256) void k_wprep2(const float* __restrict__ W_w,
                                                float* __restrict__ WT)
{
    const int idx = blockIdx.x * 256 + threadIdx.x;     // 100*128
    const int n = idx & 127, k = idx >> 7;
    WT[idx] = (n < A_) ? W_w[(size_t)n * A_ + k] : 0.f;
}

// ------------------- K1a: K-split(4) partial of seq@W2 + partial LN stats
// grid (256, 4): x = 32-row tile, y = K quarter (192 each = 6 chunks of 32).
__global__ __launch_bounds__(256) void k_lnx(
    const float* __restrict__ seq, const float* __restrict__ wT,
    float* __restrict__ part, float2* __restrict__ statp)
{
    __shared__ float ss[32][36];        // raw seq chunk, +4 pad
    __shared__ float ws[32][128];
    const int tid = threadIdx.x;
    const int row0 = blockIdx.x * 32;
    const int kz = blockIdx.y;          // K quarter
    const int kbase = kz * 6;           // chunk offset
    const int c4 = tid & 31, rg = tid >> 5;

    float4 acc[4];
    float rsum[4] = {0.f, 0.f, 0.f, 0.f};
    float rsq[4]  = {0.f, 0.f, 0.f, 0.f};
    #pragma unroll
    for (int i = 0; i < 4; ++i) { acc[i].x = acc[i].y = acc[i].z = acc[i].w = 0.f; }

    for (int kc = 0; kc < 6; ++kc) {
        {   // stage raw seq chunk: 32 rows x 32 k = 256 float4, 1/thread
            const int r = tid >> 3, k4 = tid & 7;
            *(float4*)&ss[r][k4 * 4] =
                *(const float4*)(seq + (size_t)(row0 + r) * D_ + (kbase + kc) * 32 + k4 * 4);
        }
        #pragma unroll
        for (int t = 0; t < 4; ++t) {   // stage weight chunk: 1024 float4, 4/thread
            const int idx = tid + t * 256;
            const int k = idx >> 5, cc = idx & 31;
            *(float4*)&ws[k][cc * 4] =
                *(const float4*)(wT + (size_t)(kbase + kc) * 4096 + (size_t)k * 128 + cc * 4);
        }
        __syncthreads();
        #pragma unroll 2
        for (int k = 0; k < 32; k += 4) {
            float4 sv[4];
            #pragma unroll
            for (int i = 0; i < 4; ++i) {
                sv[i] = *(float4*)&ss[rg * 4 + i][k];
                rsum[i] += sv[i].x + sv[i].y + sv[i].z + sv[i].w;
                rsq[i]  += sv[i].x * sv[i].x + sv[i].y * sv[i].y
                         + sv[i].z * sv[i].z + sv[i].w * sv[i].w;
            }
            #pragma unroll
            for (int j = 0; j < 4; ++j) {
                float4 w4 = *(float4*)&ws[k + j][c4 * 4];
                #pragma unroll
                for (int i = 0; i < 4; ++i) {
                    const float sj = ((float*)&sv[i])[j];
                    acc[i].x += sj * w4.x; acc[i].y += sj * w4.y;
                    acc[i].z += sj * w4.z; acc[i].w += sj * w4.w;
                }
            }
        }
        __syncthreads();
    }

    float* dst = part + (size_t)kz * PHALF_;
    #pragma unroll
    for (int i = 0; i < 4; ++i) {
        const int grow = row0 + rg * 4 + i;
        *(float4*)(dst + (size_t)grow * XP_ + c4 * 4) = acc[i];
        if (c4 == 0) statp[(size_t)kz * 8192 + grow] = make_float2(rsum[i], rsq[i]);
    }
}

// ------------------- K1b: combine 4 partials + LN epilogue -> xp (8 rows/block)
__global__ __launch_bounds__(256) void k_lnfin(
    const float* __restrict__ part, const float2* __restrict__ statp,
    const float* __restrict__ colsum, const float* __restrict__ basev,
    float* __restrict__ xp)
{
    const int tid = threadIdx.x;
    const int row = blockIdx.x * 8 + (tid >> 5);
    const int c4 = tid & 31;
    const float2 s0 = statp[row], s1 = statp[8192 + row];
    const float2 s2 = statp[16384 + row], s3 = statp[24576 + row];
    const float sx = s0.x + s1.x + s2.x + s3.x;
    const float sq = s0.y + s1.y + s2.y + s3.y;
    const float m = sx * (1.0f / 768.0f);
    const float var = (sq - 768.0f * m * m) * (1.0f / 767.0f);  // ddof=1
    const float rd = 1.0f / (sqrtf(var) + 1e-6f);                // std + EPS
    float4 p0 = *(const float4*)(part + (size_t)row * XP_ + c4 * 4);
    float4 p1 = *(const float4*)(part + PHALF_ + (size_t)row * XP_ + c4 * 4);
    float4 p2 = *(const float4*)(part + 2 * (size_t)PHALF_ + (size_t)row * XP_ + c4 * 4);
    float4 p3 = *(const float4*)(part + 3 * (size_t)PHALF_ + (size_t)row * XP_ + c4 * 4);
    const float4 cs4 = ((const float4*)colsum)[c4];
    const float4 bs4 = ((const float4*)basev)[c4];
    float4 o;
    o.x = rd * (p0.x + p1.x + p2.x + p3.x - m * cs4.x) + bs4.x;
    o.y = rd * (p0.y + p1.y + p2.y + p3.y - m * cs4.y) + bs4.y;
    o.z = rd * (p0.z + p1.z + p2.z + p3.z - m * cs4.z) + bs4.z;
    o.w = rd * (p0.w + p1.w + p2.w + p3.w - m * cs4.w) + bs4.w;
    *(float4*)(xp + (size_t)row * XP_ + c4 * 4) = o;   // pad cols stay 0
}

// ------------------- K2: q/k = x @ [q_w|k_w]^T + bias  (tiled GEMM); qt/kt (B,L,100)
__global__ __launch_bounds__(256) void k_qkg(
    const float* __restrict__ xp, const float* __restrict__ qkT,
    const float* __restrict__ q_b, const float* __restrict__ k_b,
    float* __restrict__ qt, float* __restrict__ kt)
{
    __shared__ float ss[32][104];
    __shared__ float ws[A_][128];
    const int tid = threadIdx.x;
    const int row0 = blockIdx.x * 32;
    const int half = blockIdx.y;
    const int c4 = tid & 31, rg = tid >> 5;

    for (int idx = tid; idx < 32 * 25; idx += 256) {
        const int r = idx / 25, k4 = idx % 25;
        *(float4*)&ss[r][k4 * 4] = *(const float4*)(xp + (size_t)(row0 + r) * XP_ + k4 * 4);
    }
    for (int idx = tid; idx < A_ * 32; idx += 256) {
        const int k = idx >> 5, cc = idx & 31;
        *(float4*)&ws[k][cc * 4] = *(const float4*)(qkT + (size_t)k * 256 + half * 128 + cc * 4);
    }
    __syncthreads();

    float4 acc[4];
    #pragma unroll
    for (int i = 0; i < 4; ++i) { acc[i].x = acc[i].y = acc[i].z = acc[i].w = 0.f; }
    #pragma unroll 5
    for (int k = 0; k < A_; k += 4) {
        float4 sv[4];
        #pragma unroll
        for (int i = 0; i < 4; ++i) sv[i] = *(float4*)&ss[rg * 4 + i][k];
        #pragma unroll
        for (int j = 0; j < 4; ++j) {
            float4 w4 = *(float4*)&ws[k + j][c4 * 4];
            #pragma unroll
            for (int i = 0; i < 4; ++i) {
                const float sj = ((float*)&sv[i])[j];
                acc[i].x += sj * w4.x; acc[i].y += sj * w4.y;
                acc[i].z += sj * w4.z; acc[i].w += sj * w4.w;
            }
        }
    }

    if (c4 < 25) {
        const float4 bias = ((const float4*)(half ? k_b : q_b))[c4];
        float* dst = half ? kt : qt;
        #pragma unroll
        for (int i = 0; i < 4; ++i) {
            float4 o;
            o.x = acc[i].x + bias.x; o.y = acc[i].y + bias.y;
            o.z = acc[i].z + bias.z; o.w = acc[i].w + bias.w;
            *(float4*)(dst + (size_t)(row0 + rg * 4 + i) * A_ + c4 * 4) = o;
        }
    }
}

// --------------- K3a: es[bh][i][j] = (mask? q.k/5 : -1e9) + syn   (64x64 tile GEMM, K=25)
__global__ __launch_bounds__(256) void k_sgemm(
    const float* __restrict__ qt, const float* __restrict__ kt,
    const float* __restrict__ syn, const int* __restrict__ src_mask,
    float* __restrict__ es)
{
    __shared__ float qs[DK_][64];
    __shared__ float ks[DK_][64];
    __shared__ int ms[64];
    const int tid = threadIdx.x;
    const int bh = blockIdx.z;
    const int b = bh >> 2, h = bh & 3;
    const int i0 = blockIdx.x * 64, j0 = blockIdx.y * 64;
    const float* qbase = qt + ((size_t)b * L_ + i0) * A_ + h * DK_;
    const float* kbase = kt + ((size_t)b * L_ + j0) * A_ + h * DK_;
    {
        const int r = tid >> 2, c = tid & 3;
        #pragma unroll
        for (int k = 0; k < 7; ++k) {
            const int d = c + 4 * k;
            if (d < DK_) {
                qs[d][r] = qbase[(size_t)r * A_ + d];
                ks[d][r] = kbase[(size_t)r * A_ + d];
            }
        }
        if (tid < 64) ms[tid] = src_mask[b * L_ + j0 + tid];
    }
    __syncthreads();
    const int ty = tid >> 4, tx = tid & 15;
    float acc[4][4] = {};
    #pragma unroll 5
    for (int d = 0; d < DK_; ++d) {
        float4 qv = *(const float4*)&qs[d][ty * 4];
        float4 kv = *(const float4*)&ks[d][tx * 4];
        const float q[4] = {qv.x, qv.y, qv.z, qv.w};
        const float kk[4] = {kv.x, kv.y, kv.z, kv.w};
        #pragma unroll
        for (int ii = 0; ii < 4; ++ii)
            #pragma unroll
            for (int jj = 0; jj < 4; ++jj)
                acc[ii][jj] += q[ii] * kk[jj];
    }
    const int irow = i0 + ty * 4, jcol = j0 + tx * 4;
    const int m0 = ms[tx * 4], m1 = ms[tx * 4 + 1], m2 = ms[tx * 4 + 2], m3 = ms[tx * 4 + 3];
    #pragma unroll
    for (int ii = 0; ii < 4; ++ii) {
        const size_t o = ((size_t)bh * L_ + irow + ii) * L_ + jcol;
        float4 sv = *(const float4*)(syn + o);
        float4 w;
        w.x = (m0 ? acc[ii][0] * 0.2f : -1e9f) + sv.x;
        w.y = (m1 ? acc[ii][1] * 0.2f : -1e9f) + sv.y;
        w.z = (m2 ? acc[ii][2] * 0.2f : -1e9f) + sv.z;
        w.w = (m3 ? acc[ii][3] * 0.2f : -1e9f) + sv.w;
        *(float4*)(es + o) = w;
    }
}

// --------------- K3b: softmax over j per (b,h,i); adjsum -> es plane0, wadj -> plane1
__global__ __launch_bounds__(256) void k_softmax(
    const float* __restrict__ Wx_w, float* __restrict__ es)
{
    __shared__ float ps[H_][L_];
    __shared__ float cs[H_];
    const int tid = threadIdx.x, r = blockIdx.x;
    const int b = r >> 9, i = r & 511;
    const int h = tid >> 6, lane = tid & 63;
    if (tid < H_) cs[tid] = Wx_w[tid] + Wx_w[204 + tid] + Wx_w[408 + tid] + Wx_w[612 + tid];
    float* row = es + (((size_t)(b * H_ + h)) * L_ + i) * L_;
    float4 v0 = ((const float4*)row)[lane];
    float4 v1 = ((const float4*)row)[lane + 64];
    float mx = fmaxf(fmaxf(fmaxf(v0.x, v0.y), fmaxf(v0.z, v0.w)),
                     fmaxf(fmaxf(v1.x, v1.y), fmaxf(v1.z, v1.w)));
    #pragma unroll
    for (int o = 32; o; o >>= 1) mx = fmaxf(mx, __shfl_xor(mx, o));
    float4 e0, e1;
    e0.x = __expf(v0.x - mx); e0.y = __expf(v0.y - mx);
    e0.z = __expf(v0.z - mx); e0.w = __expf(v0.w - mx);
    e1.x = __expf(v1.x - mx); e1.y = __expf(v1.y - mx);
    e1.z = __expf(v1.z - mx); e1.w = __expf(v1.w - mx);
    float sum = e0.x + e0.y + e0.z + e0.w + e1.x + e1.y + e1.z + e1.w;
    #pragma unroll
    for (int o = 32; o; o >>= 1) sum += __shfl_xor(sum, o);
    const float inv = 1.0f / sum;
    e0.x *= inv; e0.y *= inv; e0.z *= inv; e0.w *= inv;
    e1.x *= inv; e1.y *= inv; e1.z *= inv; e1.w *= inv;
    *(float4*)&ps[h][lane * 4] = e0;
    *(float4*)&ps[h][(lane + 64) * 4] = e1;
    __syncthreads();
    float* arow = es + (((size_t)(b * H_ + 0)) * L_ + i) * L_;
    float* wrow = es + (((size_t)(b * H_ + 1)) * L_ + i) * L_;
    const int t = tid & 127;
    float4 p0 = *(float4*)&ps[0][t * 4];
    float4 p1 = *(float4*)&ps[1][t * 4];
    float4 p2 = *(float4*)&ps[2][t * 4];
    float4 p3 = *(float4*)&ps[3][t * 4];
    if (tid < 128) {
        float4 o;
        o.x = p0.x + p1.x + p2.x + p3.x;
        o.y = p0.y + p1.y + p2.y + p3.y;
        o.z = p0.z + p1.z + p2.z + p3.z;
        o.w = p0.w + p1.w + p2.w + p3.w;
        *(float4*)(arow + t * 4) = o;
    } else {
        const float c0 = cs[0], c1 = cs[1], c2 = cs[2], c3 = cs[3];
        float4 o;
        o.x = c0 * p0.x + c1 * p1.x + c2 * p2.x + c3 * p3.x;
        o.y = c0 * p0.y + c1 * p1.y + c2 * p2.y + c3 * p3.y;
        o.z = c0 * p0.z + c1 * p1.z + c2 * p2.z + c3 * p3.z;
        o.w = c0 * p0.w + c1 * p1.w + c2 * p2.w + c3 * p3.w;
        *(float4*)(wrow + t * 4) = o;
    }
}

// ------------- K4a: partial adj@x over K quarter; grid (256, 4), 256 thr, 32-row tile
__global__ __launch_bounds__(256) void k_axp(
    const float* __restrict__ adj, const float* __restrict__ xp,
    float* __restrict__ part)
{
    __shared__ float ss[32][36];        // adj chunk, +4 pad
    __shared__ float ws[32][128];       // x chunk
    const int tid = threadIdx.x;
    const int row0 = blockIdx.x * 32;       // global row in [0, B*L)
    const int kz = blockIdx.y;              // K quarter (128 each)
    const int b = row0 >> 9, i0 = row0 & 511;
    const float* adjb = adj + (size_t)b * 4 * L_ * L_;
    const float* xpb = xp + (size_t)b * L_ * XP_ + (size_t)kz * 128 * XP_;
    const int c4 = tid & 31, rg = tid >> 5;
    float4 acc[4];
    #pragma unroll
    for (int i = 0; i < 4; ++i) { acc[i].x = acc[i].y = acc[i].z = acc[i].w = 0.f; }

    for (int kc = 0; kc < 4; ++kc) {
        {
            const int r = tid >> 3, k4 = tid & 7;
            *(float4*)&ss[r][k4 * 4] =
                *(const float4*)(adjb + (size_t)(i0 + r) * L_ + kz * 128 + kc * 32 + k4 * 4);
        }
        #pragma unroll
        for (int t = 0; t < 4; ++t) {
            const int idx = tid + t * 256;
            const int k = idx >> 5, cc = idx & 31;
            *(float4*)&ws[k][cc * 4] =
                *(const float4*)(xpb + (size_t)(kc * 32 + k) * XP_ + cc * 4);
        }
        __syncthreads();
        #pragma unroll 2
        for (int k = 0; k < 32; k += 4) {
            float4 sv[4];
            #pragma unroll
            for (int i = 0; i < 4; ++i) sv[i] = *(float4*)&ss[rg * 4 + i][k];
            #pragma unroll
            for (int j = 0; j < 4; ++j) {
                float4 w4 = *(float4*)&ws[k + j][c4 * 4];
                #pragma unroll
                for (int i = 0; i < 4; ++i) {
                    const float sj = ((float*)&sv[i])[j];
                    acc[i].x += sj * w4.x; acc[i].y += sj * w4.y;
                    acc[i].z += sj * w4.z; acc[i].w += sj * w4.w;
                }
            }
        }
        __syncthreads();
    }

    float* dst = part + (size_t)kz * PHALF_;
    #pragma unroll
    for (int i = 0; i < 4; ++i)
        *(float4*)(dst + (size_t)(row0 + rg * 4 + i) * XP_ + c4 * 4) = acc[i];
}

// ------------- K4b: xout = relu(((p0+p1+p2+p3)/H [+extras]) @ W^T + b)
template<int LAYER2>
__global__ __launch_bounds__(256) void k_xw(
    const float* __restrict__ part, const float* __restrict__ WT,
    const float* __restrict__ W_b, const float* __restrict__ S,
    const float* __restrict__ T, const float* __restrict__ Vv,
    const float* __restrict__ Wx_b, float* __restrict__ xout)
{
    __shared__ float ss[32][104];
    __shared__ float ws[A_][128];
    const int tid = threadIdx.x;
    const int row0 = blockIdx.x * 32;
    const int b = row0 >> 9;
    const int c4 = tid & 31, rg = tid >> 5;

    float wb = 0.f;
    if (LAYER2) wb = Wx_b[0] + Wx_b[1] + Wx_b[2] + Wx_b[3];

    for (int idx = tid; idx < 32 * 25; idx += 256) {
        const int r = idx / 25, k4 = idx % 25;
        const int grow = row0 + r;
        float4 a0 = *(const float4*)(part + (size_t)grow * XP_ + k4 * 4);
        float4 a1 = *(const float4*)(part + PHALF_ + (size_t)grow * XP_ + k4 * 4);
        float4 a2 = *(const float4*)(part + 2 * (size_t)PHALF_ + (size_t)grow * XP_ + k4 * 4);
        float4 a3 = *(const float4*)(part + 3 * (size_t)PHALF_ + (size_t)grow * XP_ + k4 * 4);
        float4 sum;
        sum.x = a0.x + a1.x + a2.x + a3.x;
        sum.y = a0.y + a1.y + a2.y + a3.y;
        sum.z = a0.z + a1.z + a2.z + a3.z;
        sum.w = a0.w + a1.w + a2.w + a3.w;
        float4 v;
        if (LAYER2) {
            const float4 s4 = *(const float4*)(S + b * A_ + k4 * 4);
            const float4 t4 = *(const float4*)(T + b * A_ + k4 * 4);
            const float vv = Vv[grow] + wb;
            v.x = (sum.x + s4.x + vv * t4.x) * 0.25f;
            v.y = (sum.y + s4.y + vv * t4.y) * 0.25f;
            v.z = (sum.z + s4.z + vv * t4.z) * 0.25f;
            v.w = (sum.w + s4.w + vv * t4.w) * 0.25f;
        } else {
            v.x = sum.x * 0.25f; v.y = sum.y * 0.25f;
            v.z = sum.z * 0.25f; v.w = sum.w * 0.25f;
        }
        *(float4*)&ss[r][k4 * 4] = v;
    }
    for (int idx = tid; idx < A_ * 32; idx += 256) {
        const int k = idx >> 5, cc = idx & 31;
        *(float4*)&ws[k][cc * 4] = *(const float4*)(WT + (size_t)k * 128 + cc * 4);
    }
    __syncthreads();

    float4 acc[4];
    #pragma unroll
    for (int i = 0; i < 4; ++i) { acc[i].x = acc[i].y = acc[i].z = acc[i].w = 0.f; }
    #pragma unroll 5
    for (int k = 0; k < A_; k += 4) {
        float4 sv[4];
        #pragma unroll
        for (int i = 0; i < 4; ++i) sv[i] = *(float4*)&ss[rg * 4 + i][k];
        #pragma unroll
        for (int j = 0; j < 4; ++j) {
            float4 w4 = *(float4*)&ws[k + j][c4 * 4];
            #pragma unroll
            for (int i = 0; i < 4; ++i) {
                const float sj = ((float*)&sv[i])[j];
                acc[i].x += sj * w4.x; acc[i].y += sj * w4.y;
                acc[i].z += sj * w4.z; acc[i].w += sj * w4.w;
            }
        }
    }

    float4 bias = {0.f, 0.f, 0.f, 0.f};
    if (c4 < 25) bias = ((const float4*)W_b)[c4];
    #pragma unroll
    for (int i = 0; i < 4; ++i) {
        float4 o;
        o.x = fmaxf(acc[i].x + bias.x, 0.f); o.y = fmaxf(acc[i].y + bias.y, 0.f);
        o.z = fmaxf(acc[i].z + bias.z, 0.f); o.w = fmaxf(acc[i].w + bias.w, 0.f);
        *(float4*)(xout + (size_t)(row0 + rg * 4 + i) * XP_ + c4 * 4) = o;  // WT pad -> 0
    }
}

// ---------------- K5: rank-1 extras for layer 2: Vv (B,L), T,S (B,A); zero pooled
__global__ __launch_bounds__(256) void k_extras(
    const float* __restrict__ x1, const float* __restrict__ Wx_w,
    float* __restrict__ Vv, float* __restrict__ T, float* __restrict__ S,
    float* __restrict__ pooled)
{
    __shared__ float b1s[A_], b2s[A_], Ul[L_];
    const int tid = threadIdx.x, b = blockIdx.x;
    if (tid < A_) {
        float s1 = 0.f, s2 = 0.f;
        #pragma unroll
        for (int g = 0; g < H_; ++g) {
            s1 += Wx_w[g * 204 + 4 + tid];
            s2 += Wx_w[g * 204 + 104 + tid];
        }
        b1s[tid] = s1; b2s[tid] = s2;
        pooled[b * A_ + tid] = 0.f;
    }
    __syncthreads();
    for (int j = tid; j < L_; j += 256) {
        const float* xr = x1 + ((size_t)b * L_ + j) * XP_;
        float u = 0.f, v = 0.f;
        #pragma unroll 4
        for (int c = 0; c < A_; ++c) { float xv = xr[c]; u += xv * b1s[c]; v += xv * b2s[c]; }
        Ul[j] = u;
        Vv[b * L_ + j] = v;
    }
    __syncthreads();
    if (tid < A_) {
        float t = 0.f, s = 0.f;
        for (int j = 0; j < L_; ++j) {
            float xv = x1[((size_t)b * L_ + j) * XP_ + tid];
            t += xv; s += Ul[j] * xv;
        }
        T[b * A_ + tid] = t; S[b * A_ + tid] = s;
    }
}

// ---------------- K6: pooled[b] += sum_rows relu([x,x1,x2]@agg^T + b)   (tiled GEMM)
__global__ __launch_bounds__(256) void k_nodepool(
    const float* __restrict__ x, const float* __restrict__ x1, const float* __restrict__ x2,
    const float* __restrict__ aggT, const float* __restrict__ agg_b,
    float* __restrict__ pooled)
{
    __shared__ float ss[32][104];
    __shared__ float ws[A_][128];
    const int tid = threadIdx.x;
    const int row0 = blockIdx.x * 32;
    const int b = row0 >> 9;
    const int c4 = tid & 31, rg = tid >> 5;
    float4 acc[4];
    #pragma unroll
    for (int i = 0; i < 4; ++i) { acc[i].x = acc[i].y = acc[i].z = acc[i].w = 0.f; }

    for (int c = 0; c < 3; ++c) {
        const float* src = (c == 0) ? x : (c == 1) ? x1 : x2;
        for (int idx = tid; idx < 32 * 25; idx += 256) {
            const int r = idx / 25, k4 = idx % 25;
            *(float4*)&ss[r][k4 * 4] =
                *(const float4*)(src + (size_t)(row0 + r) * XP_ + k4 * 4);
        }
        for (int idx = tid; idx < A_ * 32; idx += 256) {
            const int k = idx >> 5, cc = idx & 31;
            *(float4*)&ws[k][cc * 4] =
                *(const float4*)(aggT + ((size_t)c * A_ + k) * 128 + cc * 4);
        }
        __syncthreads();
        #pragma unroll 5
        for (int k = 0; k < A_; k += 4) {
            float4 sv[4];
            #pragma unroll
            for (int i = 0; i < 4; ++i) sv[i] = *(float4*)&ss[rg * 4 + i][k];
            #pragma unroll
            for (int j = 0; j < 4; ++j) {
                float4 w4 = *(float4*)&ws[k + j][c4 * 4];
                #pragma unroll
                for (int i = 0; i < 4; ++i) {
                    const float sj = ((float*)&sv[i])[j];
                    acc[i].x += sj * w4.x; acc[i].y += sj * w4.y;
                    acc[i].z += sj * w4.z; acc[i].w += sj * w4.w;
                }
            }
        }
        __syncthreads();
    }

    float4 bias = {0.f, 0.f, 0.f, 0.f};
    if (c4 < 25) bias = ((const float4*)agg_b)[c4];
    float4 rs = {0.f, 0.f, 0.f, 0.f};
    #pragma unroll
    for (int i = 0; i < 4; ++i) {
        rs.x += fmaxf(acc[i].x + bias.x, 0.f);
        rs.y += fmaxf(acc[i].y + bias.y, 0.f);
        rs.z += fmaxf(acc[i].z + bias.z, 0.f);
        rs.w += fmaxf(acc[i].w + bias.w, 0.f);
    }
    float* red = &ss[0][0];
    __syncthreads();
    *(float4*)&red[rg * 128 + c4 * 4] = rs;
    __syncthreads();
    if (rg == 0 && c4 < 25) {
        float4 tot = {0.f, 0.f, 0.f, 0.f};
        #pragma unroll
        for (int g = 0; g < 8; ++g) {
            float4 v = *(float4*)&red[g * 128 + c4 * 4];
            tot.x += v.x; tot.y += v.y; tot.z += v.z; tot.w += v.w;
        }
        atomicAdd(&pooled[b * A_ + c4 * 4 + 0], tot.x);
        atomicAdd(&pooled[b * A_ + c4 * 4 + 1], tot.y);
        atomicAdd(&pooled[b * A_ + c4 * 4 + 2], tot.z);
        atomicAdd(&pooled[b * A_ + c4 * 4 + 3], tot.w);
    }
}

// ---------------- K7: logits = (pooled/valid_len) @ cls^T + b
__global__ __launch_bounds__(64) void k_logits(
    const float* __restrict__ pooled, const float* __restrict__ cls_w,
    const float* __restrict__ cls_b, const int* __restrict__ mask_ids,
    float* __restrict__ out)
{
    const int tid = threadIdx.x;
    if (tid < B_ * P_) {
        const int b = tid / P_, p = tid % P_;
        int vs = 0;
        for (int l = 0; l < L_; ++l) vs += mask_ids[b * L_ + l];
        float inv = 1.0f / (float)max(vs, 1);
        float acc = cls_b[p];
        #pragma unroll 4
        for (int a = 0; a < A_; ++a) acc += (pooled[b * A_ + a] * inv) * cls_w[p * A_ + a];
        out[b * P_ + p] = acc;
    }
}

extern "C" void kernel_launch(void* const* d_in, const int* in_sizes, int n_in,
                              void* d_out, int out_size, void* d_ws, size_t ws_size,
                              hipStream_t stream) {
    const float* seq    = (const float*)d_in[0];
    const float* syn    = (const float*)d_in[1];
    const float* ln_a   = (const float*)d_in[2];
    const float* ln_b   = (const float*)d_in[3];
    const float* Wxx_w  = (const float*)d_in[4];
    const float* Wxx_b  = (const float*)d_in[5];
    const float* q_w    = (const float*)d_in[6];
    const float* q_b    = (const float*)d_in[7];
    const float* k_w    = (const float*)d_in[8];
    const float* k_b    = (const float*)d_in[9];
    const float* W_w    = (const float*)d_in[10];
    const float* W_b    = (const float*)d_in[11];
    const float* Wx_w   = (const float*)d_in[12];
    const float* Wx_b   = (const float*)d_in[13];
    const float* agg_w  = (const float*)d_in[14];
    const float* agg_b  = (const float*)d_in[15];
    const float* cls_w  = (const float*)d_in[16];
    const float* cls_b  = (const float*)d_in[17];
    const int* mask_ids = (const int*)d_in[18];
    const int* src_mask = (const int*)d_in[19];
    float* out = (float*)d_out;

    float* ws = (float*)d_ws;
    size_t off = 0;
    float* xp     = ws + off; off += (size_t)B_ * L_ * XP_;
    float* x1p    = ws + off; off += (size_t)B_ * L_ * XP_;
    float* x2p    = ws + off; off += (size_t)B_ * L_ * XP_;
    float* part   = ws + off; off += (size_t)4 * PHALF_;     // shared by lnx & axp phases
    float* qt     = ws + off; off += (size_t)B_ * L_ * A_;
    float* kt     = ws + off; off += (size_t)B_ * L_ * A_;
    float* es     = ws + off; off += (size_t)B_ * H_ * L_ * L_;
    float* Vv     = ws + off; off += (size_t)B_ * L_;
    float* T      = ws + off; off += (size_t)B_ * A_;
    float* S      = ws + off; off += (size_t)B_ * A_;
    float* pooled = ws + off; off += (size_t)B_ * A_;
    float* wT     = ws + off; off += (size_t)D_ * 128;
    float* aggT   = ws + off; off += (size_t)3 * A_ * 128;
    float* qkT    = ws + off; off += (size_t)A_ * 256;
    float* WT     = ws + off; off += (size_t)A_ * 128;
    float* colsum = ws + off; off += 128;
    float* basev  = ws + off; off += 128;
    float2* statp = (float2*)(ws + off); off += 4 * 8192 * 2;

    k_wprep<<<(D_ * 128) / 256, 256, 0, stream>>>(Wxx_w, ln_a, wT);
    k_vecprep<<<1, 128, 0, stream>>>(Wxx_w, ln_a, ln_b, Wxx_b, colsum, basev);
    k_aggprep<<<(3 * A_ * 128) / 256, 256, 0, stream>>>(agg_w, aggT);
    k_qkprep<<<(A_ * 256) / 256, 256, 0, stream>>>(q_w, k_w, qkT);
    k_wprep2<<<(A_ * 128) / 256, 256, 0, stream>>>(W_w, WT);
    k_lnx<<<dim3((B_ * L_) / 32, 4), 256, 0, stream>>>(seq, wT, part, statp);
    k_lnfin<<<(B_ * L_) / 8, 256, 0, stream>>>(part, statp, colsum, basev, xp);
    k_qkg<<<dim3((B_ * L_) / 32, 2), 256, 0, stream>>>(xp, qkT, q_b, k_b, qt, kt);
    k_sgemm<<<dim3(8, 8, B_ * H_), 256, 0, stream>>>(qt, kt, syn, src_mask, es);
    k_softmax<<<B_ * L_, 256, 0, stream>>>(Wx_w, es);
    k_axp<<<dim3((B_ * L_) / 32, 4), 256, 0, stream>>>(es, xp, part);
    k_xw<0><<<(B_ * L_) / 32, 256, 0, stream>>>(part, WT, W_b,
                                                nullptr, nullptr, nullptr, nullptr, x1p);
    k_extras<<<B_, 256, 0, stream>>>(x1p, Wx_w, Vv, T, S, pooled);
    k_axp<<<dim3((B_ * L_) / 32, 4), 256, 0, stream>>>(es + (size_t)L_ * L_, x1p, part);
    k_xw<1><<<(B_ * L_) / 32, 256, 0, stream>>>(part, WT, W_b, S, T, Vv, Wx_b, x2p);
    k_nodepool<<<(B_ * L_) / 32, 256, 0, stream>>>(xp, x1p, x2p, aggT, agg_b, pooled);
    k_logits<<<1, 64, 0, stream>>>(pooled, cls_w, cls_b, mask_ids, out);
}